// Round 3
// baseline (429.940 us; speedup 1.0000x reference)
//
#include <hip/hip_runtime.h>
#include <math.h>

// Problem constants
#define B_ 8
#define C_ 256
#define H_ 56
#define W_ 56
#define N_ 3136  // 56*56 = 49*64
#define BN_ (B_*N_)

typedef __attribute__((ext_vector_type(8))) short short8;
typedef __attribute__((ext_vector_type(4))) float f32x4;
typedef __attribute__((ext_vector_type(16))) float f32x16;
typedef __attribute__((ext_vector_type(4))) unsigned short u16x4;
#define MFMA16(A, Bf, Cf) __builtin_amdgcn_mfma_f32_16x16x32_bf16((A), (Bf), (Cf), 0, 0, 0)
#define MFMA32(A, Bf, Cf) __builtin_amdgcn_mfma_f32_32x32x16_bf16((A), (Bf), (Cf), 0, 0, 0)

// -------------------- workspace layout (ushort units) --------------------
#define XT_ELEMS (B_*58*64*256)           // 7,602,176
#define A_ELEMS  (320*2304)               // 737,280
#define AHI_OFF  (2*XT_ELEMS)
#define ALO_OFF  (AHI_OFF + A_ELEMS)
#define QKT_HI_OFF (ALO_OFF + A_ELEMS)
#define QKT_ELEMS  (B_*N_*64)             // 1,605,632 = QF_ELEMS + KF_ELEMS
#define QKT_LO_OFF (QKT_HI_OFF + QKT_ELEMS)
#define VBF_OFF    (QKT_LO_OFF + QKT_ELEMS)
#define VBF_ELEMS  (B_*C_*N_)             // 6,422,528

// Fragment-order layouts: attn lane L reads base + L*16B.
// Qf: [b][q16 (pix>>4, 196)][fq*16 + ln (64)][8]   (features 0..31)
// Kf: [b][jt (49)][tj (4)][fq*16 + ln (64)][8]     (features 32..63)
// Vf: [b][cg (8)][jt (49)][s (4)][hh*32 + c31 (64)][8]
#define QF_ELEMS (B_*196*64*8)            // 802,816

// conv staging: 3 rows x 36 cols x 4 chunks of 8ch (uint4 units), dbuf
#define NSTG 432                          // 3*36*4
#define SWZ3(r, c, c8) ((((r)*36 + (c))*4) + ((c8) ^ ((c) & 3)))

// P LDS row stride (ushorts) for attn
#define PSTR 76
// Vs (conv v-epilogue LDS transpose) pixel stride: 17*c31 mod 32 bijective banks
#define VSTR 34

__device__ inline unsigned short f2bf(float f) {
    unsigned u = __float_as_uint(f);
    unsigned r = (u + 0x7fffu + ((u >> 16) & 1u)) >> 16;   // RNE
    return (unsigned short)r;
}
__device__ inline float bf2f(unsigned short h) {
    return __uint_as_float(((unsigned)h) << 16);
}

// ---------------------------------------------------------------------------
// Kernel 0: zero the padded x regions.
// ---------------------------------------------------------------------------
__global__ __launch_bounds__(256) void zero_pads(uint4* __restrict__ p, int n16)
{
    const int stride = gridDim.x * 256;
    for (int i = blockIdx.x * 256 + threadIdx.x; i < n16; i += stride)
        p[i] = make_uint4(0, 0, 0, 0);
}

// ---------------------------------------------------------------------------
// Kernel 1a: x (fp32 NCHW) -> padded pixel-major bf16 hi/lo.
// ---------------------------------------------------------------------------
__global__ __launch_bounds__(256) void prep_x(
    const float* __restrict__ x,
    unsigned short* __restrict__ xhi, unsigned short* __restrict__ xlo)
{
    __shared__ float xs[64][57];
    const int cc = blockIdx.x, y = blockIdx.y, b = blockIdx.z;
    const int t = threadIdx.x;
    const int c0 = cc * 64;
    for (int idx = t; idx < 64 * 56; idx += 256) {
        const int ch = idx / 56, xc = idx - ch * 56;
        xs[ch][xc] = x[((size_t)(b*C_ + c0 + ch)*H_ + y)*W_ + xc];
    }
    __syncthreads();
    for (int idx = t; idx < 56 * 32; idx += 256) {
        const int xc = idx >> 5, chp = idx & 31;
        const float v0 = xs[2*chp][xc], v1 = xs[2*chp + 1][xc];
        const unsigned short h0 = f2bf(v0), h1 = f2bf(v1);
        const unsigned short l0 = f2bf(v0 - bf2f(h0));
        const unsigned short l1 = f2bf(v1 - bf2f(h1));
        const size_t o = ((size_t)(b*58 + y + 1) * 64 + (xc + 1)) * 256 + c0 + 2*chp;
        *(unsigned*)(xhi + o) = (unsigned)h0 | ((unsigned)h1 << 16);
        *(unsigned*)(xlo + o) = (unsigned)l0 | ((unsigned)l1 << 16);
    }
}

// ---------------------------------------------------------------------------
// Kernel 1b: weights -> A_hi/A_lo [320][2304], k = s*256 + c.
// ---------------------------------------------------------------------------
__global__ __launch_bounds__(256) void prep_w(
    const float* __restrict__ wq, const float* __restrict__ wk,
    const float* __restrict__ wv,
    unsigned short* __restrict__ Ahi, unsigned short* __restrict__ Alo)
{
    const int g = blockIdx.x * 256 + threadIdx.x;
    if (g >= 320 * 2304) return;
    const int m = g / 2304, k = g - m * 2304;
    const int s = k >> 8, c = k & 255;
    float w;
    if (m < 32)      w = wq[((size_t)m*C_ + c)*9 + s];
    else if (m < 64) w = wk[((size_t)(m-32)*C_ + c)*9 + s];
    else             w = wv[((size_t)(m-64)*C_ + c)*9 + s];
    const unsigned short h = f2bf(w);
    Ahi[g] = h;
    Alo[g] = f2bf(w - bf2f(h));
}

// ---------------------------------------------------------------------------
// Kernel 2: FUSED conv, R3 restructure. grid (b 8, y 56, z 4), block 256.
//   z 0..1 -> q/k path (hi/lo 3-MFMA), xh = z
//   z 2..3 -> v path, ALL 256 channels (4 mt tiles/wave), xh = z-2
// Pixel split 32+24 (8-aligned). Single-barrier double-buffered staging.
// v epilogue: LDS transpose -> dense short8 stores (R2 wrote scattered 2B
// scalars -> ~205MB phantom HBM writes, 12x amplification).
// ---------------------------------------------------------------------------
__global__ __launch_bounds__(256, 5) void conv_fused(
    const unsigned short* __restrict__ xhi, const unsigned short* __restrict__ xlo,
    const unsigned short* __restrict__ Ahi, const unsigned short* __restrict__ Alo,
    const float* __restrict__ bq, const float* __restrict__ bk,
    const float* __restrict__ bv,
    unsigned short* __restrict__ qkt_hi, unsigned short* __restrict__ qkt_lo,
    unsigned short* __restrict__ vbf)
{
    __shared__ uint4 SB[2][2][NSTG];   // [hi/lo][dbuf][slab] = 27.6 KB
    const int b = blockIdx.x, y = blockIdx.y, z = blockIdx.z;
    const int xh = z & 1;
    const int npx = xh ? 24 : 32;      // pixels this block owns (8-aligned split)
    const int t = threadIdx.x;
    const int w = t >> 6, L = t & 63;
    const int ln = L & 15, quad = L >> 4;

    // staging-thread mapping (idx < NSTG): r 0..2, colL 0..35, c8 0..3
    const int sidx0 = t, sidx1 = t + 256;
    const int sr0 = sidx0 / 144, srem0 = sidx0 - sr0*144;
    const int sc0 = srem0 >> 2, s80 = sidx0 & 3;
    const int sr1 = sidx1 / 144, srem1 = sidx1 - sr1*144;
    const int sc1 = srem1 >> 2, s81 = sidx1 & 3;
    const size_t gbase0 = ((size_t)((b*58 + y + sr0)*64 + xh*32 + sc0))*256 + s80*8;
    const size_t gbase1 = ((size_t)((b*58 + y + sr1)*64 + xh*32 + sc1))*256 + s81*8;

    if (z < 2) {
        // ---------------- q/k path (hi/lo 3-MFMA) ----------------
        f32x4 acc[2];
        acc[0] = (f32x4)0.0f; acc[1] = (f32x4)0.0f;

        uint4 ph[2], pl[2];
        // prologue: load cc=0, write buf 0
        ph[0] = *(const uint4*)(xhi + gbase0);
        pl[0] = *(const uint4*)(xlo + gbase0);
        if (sidx1 < NSTG) {
            ph[1] = *(const uint4*)(xhi + gbase1);
            pl[1] = *(const uint4*)(xlo + gbase1);
        }
        SB[0][0][SWZ3(sr0, sc0, s80)] = ph[0];
        SB[1][0][SWZ3(sr0, sc0, s80)] = pl[0];
        if (sidx1 < NSTG) {
            SB[0][0][SWZ3(sr1, sc1, s81)] = ph[1];
            SB[1][0][SWZ3(sr1, sc1, s81)] = pl[1];
        }

        for (int cc = 0; cc < 8; cc++) {
            const int buf = cc & 1;
            if (cc < 7) {   // issue next-chunk loads (in flight across barrier)
                ph[0] = *(const uint4*)(xhi + gbase0 + (cc+1)*32);
                pl[0] = *(const uint4*)(xlo + gbase0 + (cc+1)*32);
                if (sidx1 < NSTG) {
                    ph[1] = *(const uint4*)(xhi + gbase1 + (cc+1)*32);
                    pl[1] = *(const uint4*)(xlo + gbase1 + (cc+1)*32);
                }
            }
            __syncthreads();   // SB[buf] ready
#pragma unroll
            for (int s = 0; s < 9; s++) {
                const int dy = s / 3 - 1, dx = s % 3 - 1;
                const size_t aoff = (size_t)(w*16 + ln)*2304 + s*256 + cc*32 + quad*8;
                const short8 ah = *(const short8*)(Ahi + aoff);
                const short8 al = *(const short8*)(Alo + aoff);
                const int r = dy + 1;
#pragma unroll
                for (int nt = 0; nt < 2; nt++) {
                    const int colL = nt*16 + ln + dx + 1;
                    const int i4 = SWZ3(r, colL, quad);
                    const short8 bh = *(const short8*)&SB[0][buf][i4];
                    const short8 bl = *(const short8*)&SB[1][buf][i4];
                    acc[nt] = MFMA16(ah, bh, acc[nt]);
                    acc[nt] = MFMA16(ah, bl, acc[nt]);
                    acc[nt] = MFMA16(al, bh, acc[nt]);
                }
            }
            if (cc < 7) {      // write next buf (overlaps other waves' compute)
                SB[0][buf^1][SWZ3(sr0, sc0, s80)] = ph[0];
                SB[1][buf^1][SWZ3(sr0, sc0, s80)] = pl[0];
                if (sidx1 < NSTG) {
                    SB[0][buf^1][SWZ3(sr1, sc1, s81)] = ph[1];
                    SB[1][buf^1][SWZ3(sr1, sc1, s81)] = pl[1];
                }
            }
        }

        // epilogue: fragment-order Qf/Kf writes (u16x4, dense-ish)
#pragma unroll
        for (int nt = 0; nt < 2; nt++) {
            const int pxl = nt*16 + ln;
            if (pxl >= npx) continue;
            const int pix = y*56 + xh*32 + pxl;
            u16x4 hi4, lo4;
#pragma unroll
            for (int r = 0; r < 4; r++) {
                const int m = w*16 + quad*4 + r;
                const float bias = (m < 32) ? bq[m] : bk[m - 32];
                const float val = acc[nt][r] + bias;
                const unsigned short h = f2bf(val);
                hi4[r] = h;
                lo4[r] = f2bf(val - bf2f(h));
            }
            const int m0 = w*16 + quad*4;
            size_t o;
            if (w < 2) {
                o = ((size_t)(b*196 + (pix >> 4))*64 + (m0 >> 3)*16 + (pix & 15))*8 + (m0 & 7);
            } else {
                const int mk0 = m0 - 32;
                o = (size_t)QF_ELEMS +
                    (((size_t)(b*49 + (pix >> 6))*4 + ((pix >> 4) & 3))*64
                     + (mk0 >> 3)*16 + (pix & 15))*8 + (mk0 & 7);
            }
            *(u16x4*)(qkt_hi + o) = hi4;
            *(u16x4*)(qkt_lo + o) = lo4;
        }
    } else {
        // ---------------- v path: all 256 channels, 4 mt tiles/wave ----------
        f32x4 acc[4][2];
#pragma unroll
        for (int mt = 0; mt < 4; mt++) { acc[mt][0] = (f32x4)0.0f; acc[mt][1] = (f32x4)0.0f; }

        uint4 ph[2];
        ph[0] = *(const uint4*)(xhi + gbase0);
        if (sidx1 < NSTG) ph[1] = *(const uint4*)(xhi + gbase1);
        SB[0][0][SWZ3(sr0, sc0, s80)] = ph[0];
        if (sidx1 < NSTG) SB[0][0][SWZ3(sr1, sc1, s81)] = ph[1];

        for (int cc = 0; cc < 8; cc++) {
            const int buf = cc & 1;
            if (cc < 7) {
                ph[0] = *(const uint4*)(xhi + gbase0 + (cc+1)*32);
                if (sidx1 < NSTG) ph[1] = *(const uint4*)(xhi + gbase1 + (cc+1)*32);
            }
            __syncthreads();
#pragma unroll
            for (int s = 0; s < 9; s++) {
                const int dy = s / 3 - 1, dx = s % 3 - 1;
                const int r = dy + 1;
                short8 a[4];
#pragma unroll
                for (int mt = 0; mt < 4; mt++) {
                    const size_t aoff = (size_t)(64 + mt*64 + w*16 + ln)*2304
                                        + s*256 + cc*32 + quad*8;
                    a[mt] = *(const short8*)(Ahi + aoff);
                }
#pragma unroll
                for (int nt = 0; nt < 2; nt++) {
                    const int colL = nt*16 + ln + dx + 1;
                    const short8 bf = *(const short8*)&SB[0][buf][SWZ3(r, colL, quad)];
#pragma unroll
                    for (int mt = 0; mt < 4; mt++)
                        acc[mt][nt] = MFMA16(a[mt], bf, acc[mt][nt]);
                }
            }
            if (cc < 7) {
                SB[0][buf^1][SWZ3(sr0, sc0, s80)] = ph[0];
                if (sidx1 < NSTG) SB[0][buf^1][SWZ3(sr1, sc1, s81)] = ph[1];
            }
        }

        // ---- epilogue: LDS transpose -> dense Vf tile stores ----
        __syncthreads();   // all waves done reading SB
        unsigned short* Vs = (unsigned short*)&SB[0][0][0];   // [256][VSTR]
#pragma unroll
        for (int mt = 0; mt < 4; mt++)
#pragma unroll
            for (int nt = 0; nt < 2; nt++) {
                const int pxl = nt*16 + ln;
                if (pxl >= npx) continue;
#pragma unroll
                for (int r = 0; r < 4; r++) {
                    const int c = mt*64 + w*16 + quad*4 + r;
                    Vs[c*VSTR + pxl] = f2bf(acc[mt][nt][r] + bv[c]);
                }
            }
        __syncthreads();
        // readback + dense stores: lane L = (hh, c31) writes 8 pixels x 1 ch = 16B
        const int p0 = y*56 + xh*32;
        const int hh = L >> 5, c31 = L & 31;
        const int gend = (p0 + npx - 1) >> 4;
        for (int g = p0 >> 4; g <= gend; g++) {
            const int pxl0 = g*16 + hh*8 - p0;
            const bool valid = (pxl0 >= 0) && (pxl0 + 8 <= npx);
            if (valid) {
                const int jt = g >> 2, s4 = g & 3;
#pragma unroll
                for (int cg = 0; cg < 8; cg++) {
                    const int c = cg*32 + c31;
                    const short8 vv = *(const short8*)&Vs[c*VSTR + pxl0];
                    const size_t o = ((((size_t)(b*8 + cg)*49 + jt)*4 + s4)*64 + L)*8;
                    *(short8*)(vbf + o) = vv;
                }
            }
        }
    }
}

// ---------------------------------------------------------------------------
// Kernel 3: fused flash attention, 2-wave blocks (i-tile 32).
// grid (98*8, chalf 2, jh 2) = 3136 blocks, block 128 = 2 waves.
// All Q/K/V loads fragment-order coalesced (R2 win; unchanged).
// ---------------------------------------------------------------------------
__global__ __launch_bounds__(128, 4) void attn_flash2w(
    const unsigned short* __restrict__ qkt_hi, const unsigned short* __restrict__ qkt_lo,
    const unsigned short* __restrict__ vbf,
    unsigned short* __restrict__ op0, unsigned short* __restrict__ op1,
    float* __restrict__ mlbase)
{
    __shared__ unsigned short P[2][32*PSTR];   // 9.5 KB
    __shared__ float alphaL[2][32];

    const int bx = blockIdx.x;
    const int b = bx & 7, it = bx >> 3;
    const int chalf = blockIdx.y;
    const int jh = blockIdx.z;
    const int jt0 = jh * 25, njt = 25 - jh;    // 25 / 24 tiles
    const int i_base = it * 32;
    const int t = threadIdx.x;
    const int w = t >> 6, L = t & 63;
    const int ln = L & 15, quad = L >> 4;
    const int l32 = L & 31, h32 = L >> 5;

    const unsigned short* Kf_hi = qkt_hi + QF_ELEMS;
    const unsigned short* Kf_lo = qkt_lo + QF_ELEMS;

    const size_t qoff = ((size_t)(b*196 + it*2 + w)*64 + L)*8;
    const short8 qh = *(const short8*)(qkt_hi + qoff);
    const short8 ql = *(const short8*)(qkt_lo + qoff);

    float m_run = -INFINITY, l_run = 0.0f;
    f32x16 O0 = (f32x16)0.0f, O1 = (f32x16)0.0f;
    const int cg0 = chalf*4 + w*2;
    const unsigned short* vt0 = vbf + ((size_t)(b*8 + cg0)*49)*2048 + (size_t)L*8;
    const unsigned short* vt1 = vbf + ((size_t)(b*8 + cg0 + 1)*49)*2048 + (size_t)L*8;
    const unsigned short* kbh = Kf_hi + (size_t)b*49*2048 + (size_t)L*8;
    const unsigned short* kbl = Kf_lo + (size_t)b*49*2048 + (size_t)L*8;

    for (int jtl = 0; jtl < njt; jtl++) {
        const int jt = jt0 + jtl;
        const int buf = jtl & 1;

        short8 Va[4], Vb[4];
#pragma unroll
        for (int s = 0; s < 4; s++) {
            Va[s] = *(const short8*)(vt0 + jt*2048 + s*512);
            Vb[s] = *(const short8*)(vt1 + jt*2048 + s*512);
        }

        f32x4 sacc[4];
#pragma unroll
        for (int tj = 0; tj < 4; tj++) {
            const short8 kh = *(const short8*)(kbh + jt*2048 + tj*512);
            const short8 kl = *(const short8*)(kbl + jt*2048 + tj*512);
            f32x4 a = (f32x4)0.0f;
            a = MFMA16(kh, qh, a);
            a = MFMA16(kh, ql, a);
            a = MFMA16(kl, qh, a);
            sacc[tj] = a;
        }
        float mt0 = fmaxf(fmaxf(sacc[0][0], sacc[0][1]), fmaxf(sacc[0][2], sacc[0][3]));
        float mt1 = fmaxf(fmaxf(sacc[1][0], sacc[1][1]), fmaxf(sacc[1][2], sacc[1][3]));
        float mt2 = fmaxf(fmaxf(sacc[2][0], sacc[2][1]), fmaxf(sacc[2][2], sacc[2][3]));
        float mt3 = fmaxf(fmaxf(sacc[3][0], sacc[3][1]), fmaxf(sacc[3][2], sacc[3][3]));
        float mx = fmaxf(fmaxf(mt0, mt1), fmaxf(mt2, mt3));
        mx = fmaxf(mx, __shfl_xor(mx, 16));
        mx = fmaxf(mx, __shfl_xor(mx, 32));
        const float m_new = fmaxf(m_run, mx);
        const float alpha = __expf(m_run - m_new);
        m_run = m_new;

#pragma unroll
        for (int tj = 0; tj < 4; tj++)
#pragma unroll
            for (int r = 0; r < 4; r++)
                sacc[tj][r] = __expf(sacc[tj][r] - m_new);
        float s0 = (sacc[0][0] + sacc[0][1]) + (sacc[0][2] + sacc[0][3]);
        float s1 = (sacc[1][0] + sacc[1][1]) + (sacc[1][2] + sacc[1][3]);
        float s2 = (sacc[2][0] + sacc[2][1]) + (sacc[2][2] + sacc[2][3]);
        float s3 = (sacc[3][0] + sacc[3][1]) + (sacc[3][2] + sacc[3][3]);
        float ps = (s0 + s1) + (s2 + s3);
        ps += __shfl_xor(ps, 16);
        ps += __shfl_xor(ps, 32);
        l_run = l_run * alpha + ps;

        {
            unsigned short* prow = &P[buf][(w*16 + ln)*PSTR];
#pragma unroll
            for (int tj = 0; tj < 4; tj++) {
                u16x4 pk;
#pragma unroll
                for (int r = 0; r < 4; r++) pk[r] = f2bf(sacc[tj][r]);
                *(u16x4*)(prow + tj*16 + quad*4) = pk;
            }
        }
        if (quad == 0) alphaL[buf][w*16 + ln] = alpha;

        __syncthreads();

        const float a = alphaL[buf][l32];
        if (__any(a != 1.0f)) {
#pragma unroll
            for (int rg = 0; rg < 16; rg++) { O0[rg] *= a; O1[rg] *= a; }
        }
        short8 Bp[4];
#pragma unroll
        for (int s = 0; s < 4; s++) {
            Bp[s] = *(const short8*)&P[buf][l32*PSTR + s*16 + h32*8];
            O0 = MFMA32(Va[s], Bp[s], O0);
        }
#pragma unroll
        for (int s = 0; s < 4; s++)
            O1 = MFMA32(Vb[s], Bp[s], O1);
    }

    if (chalf == 0 && quad == 0) {
        const int i = i_base + w*16 + ln;
        mlbase[jh*BN_ + b*N_ + i]       = m_run;
        mlbase[(2 + jh)*BN_ + b*N_ + i] = l_run;
    }
    unsigned short* OP = jh ? op1 : op0;
    const int pix = i_base + l32;
#pragma unroll
    for (int g = 0; g < 2; g++) {
        const f32x16 Ot = g ? O1 : O0;
        const int cg = chalf*128 + w*64 + g*32;
#pragma unroll
        for (int reg = 0; reg < 16; reg++) {
            const int c = cg + (reg & 3) + 8*(reg >> 2) + 4*h32;
            OP[(size_t)(b*C_ + c)*N_ + pix] = f2bf(Ot[reg]);
        }
    }
}

// ---------------------------------------------------------------------------
// Kernel 4: combine the two j-half partials + residual.
// ---------------------------------------------------------------------------
__global__ __launch_bounds__(256) void combine(
    const unsigned short* __restrict__ op0, const unsigned short* __restrict__ op1,
    const float* __restrict__ mlbase,
    const float* __restrict__ x, const float* __restrict__ gptr,
    float* __restrict__ out)
{
    const int bid = blockIdx.x;
    const int b = bid / 49, pt = bid - b*49;
    const int ch2 = blockIdx.y;
    const int t = threadIdx.x;
    const int pix = pt*64 + (t & 63);
    const int cofs = t >> 6;

    const float m0 = mlbase[b*N_ + pix];
    const float m1 = mlbase[BN_ + b*N_ + pix];
    const float l0 = mlbase[2*BN_ + b*N_ + pix];
    const float l1 = mlbase[3*BN_ + b*N_ + pix];
    const float mm = fmaxf(m0, m1);
    const float a0 = __expf(m0 - mm), a1 = __expf(m1 - mm);
    const float gamma = gptr[0];
    const float inv = gamma / (a0*l0 + a1*l1);
    const float c0 = a0 * inv, c1 = a1 * inv;

    for (int ci = 0; ci < 32; ci++) {
        const int c = ch2*128 + cofs + ci*4;
        const size_t idx = (size_t)(b*C_ + c)*N_ + pix;
        const float o = c0 * bf2f(op0[idx]) + c1 * bf2f(op1[idx]);
        out[idx] = x[idx] + o;
    }
}

// ---------------------------------------------------------------------------
extern "C" void kernel_launch(void* const* d_in, const int* in_sizes, int n_in,
                              void* d_out, int out_size, void* d_ws, size_t ws_size,
                              hipStream_t stream)
{
    (void)in_sizes; (void)n_in; (void)out_size; (void)ws_size;
    const float* x  = (const float*)d_in[0];
    const float* wq = (const float*)d_in[1];
    const float* bq = (const float*)d_in[2];
    const float* wk = (const float*)d_in[3];
    const float* bk = (const float*)d_in[4];
    const float* wv = (const float*)d_in[5];
    const float* bv = (const float*)d_in[6];
    const float* gm = (const float*)d_in[7];
    float* out = (float*)d_out;

    unsigned short* u = (unsigned short*)d_ws;
    unsigned short* xhi = u;                      // conv input; later O-partial jh=0
    unsigned short* xlo = u + XT_ELEMS;           // conv input; later O-partial jh=1
    unsigned short* Ahi = u + AHI_OFF;            // weights; first 400KB later m/l
    unsigned short* Alo = u + ALO_OFF;
    unsigned short* qkt_hi = u + QKT_HI_OFF;      // [Qf_hi | Kf_hi] fragment-order
    unsigned short* qkt_lo = u + QKT_LO_OFF;      // [Qf_lo | Kf_lo]
    unsigned short* vbf = u + VBF_OFF;            // Vf fragment-order
    float* mlbase = (float*)Ahi;                  // 4 * B*N floats = 401 KB

    hipLaunchKernelGGL(zero_pads, dim3(1024), dim3(256), 0, stream,
                       (uint4*)d_ws, (2*XT_ELEMS*2)/16);
    hipLaunchKernelGGL(prep_x, dim3(4, 56, 8), dim3(256), 0, stream, x, xhi, xlo);
    hipLaunchKernelGGL(prep_w, dim3(2880), dim3(256), 0, stream, wq, wk, wv, Ahi, Alo);
    hipLaunchKernelGGL(conv_fused, dim3(8, 56, 4), dim3(256), 0, stream,
                       xhi, xlo, Ahi, Alo, bq, bk, bv, qkt_hi, qkt_lo, vbf);
    hipLaunchKernelGGL(attn_flash2w, dim3(98*8, 2, 2), dim3(128), 0, stream,
                       qkt_hi, qkt_lo, vbf, xhi, xlo, mlbase);
    hipLaunchKernelGGL(combine, dim3(392, 2), dim3(256), 0, stream,
                       xhi, xlo, mlbase, x, gm, out);
}

// Round 4
// 343.063 us; speedup vs baseline: 1.2532x; 1.2532x over previous
//
#include <hip/hip_runtime.h>
#include <math.h>

// Problem constants
#define B_ 8
#define C_ 256
#define H_ 56
#define W_ 56
#define N_ 3136  // 56*56 = 49*64
#define BN_ (B_*N_)

typedef __attribute__((ext_vector_type(8))) short short8;
typedef __attribute__((ext_vector_type(4))) float f32x4;
typedef __attribute__((ext_vector_type(16))) float f32x16;
typedef __attribute__((ext_vector_type(4))) unsigned short u16x4;
#define MFMA16(A, Bf, Cf) __builtin_amdgcn_mfma_f32_16x16x32_bf16((A), (Bf), (Cf), 0, 0, 0)
#define MFMA32(A, Bf, Cf) __builtin_amdgcn_mfma_f32_32x32x16_bf16((A), (Bf), (Cf), 0, 0, 0)

// -------------------- workspace layout (ushort units) --------------------
#define XT_ELEMS (B_*58*64*256)           // 7,602,176
#define A_ELEMS  (320*2304)               // 737,280
#define AHI_OFF  (2*XT_ELEMS)
#define ALO_OFF  (AHI_OFF + A_ELEMS)
#define QKT_HI_OFF (ALO_OFF + A_ELEMS)
#define QKT_ELEMS  (B_*N_*64)             // 1,605,632 = QF_ELEMS + KF_ELEMS
#define QKT_LO_OFF (QKT_HI_OFF + QKT_ELEMS)
#define VBF_OFF    (QKT_LO_OFF + QKT_ELEMS)
#define VBF_ELEMS  (B_*C_*N_)             // 6,422,528

// Fragment-order layouts: attn lane L reads base + L*16B.
// Qf: [b][q16 (pix>>4, 196)][fq*16 + ln (64)][8]   (features 0..31)
// Kf: [b][jt (49)][tj (4)][fq*16 + ln (64)][8]     (features 32..63)
// Vf: [b][cg (8)][jt (49)][s (4)][hh*32 + c31 (64)][8]
#define QF_ELEMS (B_*196*64*8)            // 802,816

// Af fragment-order weights (R4): [rowgrp 20][s 9][cc 8][L 64][8]
// rowgrp = m>>4 (qk rows 0..63 -> g 0..3; v rows 64..319 -> g 4..19).
// Conv A-load = one dense 1KB burst per wave (was a 16-line scatter at
// 4.6KB lane stride -> TA transaction serialization).

// LDS swizzle for conv B-slabs: chunk (r,col,c8) -> uint4 index
#define SWZ(r, col, c8) ((((r)*64 + (col))*4) + ((c8) ^ ((col) & 3)))

// P LDS row stride (ushorts) for attn
#define PSTR 76
// Vs (conv v-epilogue LDS transpose) pixel stride: 29 dwords, coprime 32 banks
#define VSTR 58

__device__ inline unsigned short f2bf(float f) {
    unsigned u = __float_as_uint(f);
    unsigned r = (u + 0x7fffu + ((u >> 16) & 1u)) >> 16;   // RNE
    return (unsigned short)r;
}
__device__ inline float bf2f(unsigned short h) {
    return __uint_as_float(((unsigned)h) << 16);
}

// ---------------------------------------------------------------------------
// Kernel 0: zero the padded x regions.
// ---------------------------------------------------------------------------
__global__ __launch_bounds__(256) void zero_pads(uint4* __restrict__ p, int n16)
{
    const int stride = gridDim.x * 256;
    for (int i = blockIdx.x * 256 + threadIdx.x; i < n16; i += stride)
        p[i] = make_uint4(0, 0, 0, 0);
}

// ---------------------------------------------------------------------------
// Kernel 1a: x (fp32 NCHW) -> padded pixel-major bf16 hi/lo.
// ---------------------------------------------------------------------------
__global__ __launch_bounds__(256) void prep_x(
    const float* __restrict__ x,
    unsigned short* __restrict__ xhi, unsigned short* __restrict__ xlo)
{
    __shared__ float xs[64][57];
    const int cc = blockIdx.x, y = blockIdx.y, b = blockIdx.z;
    const int t = threadIdx.x;
    const int c0 = cc * 64;
    for (int idx = t; idx < 64 * 56; idx += 256) {
        const int ch = idx / 56, xc = idx - ch * 56;
        xs[ch][xc] = x[((size_t)(b*C_ + c0 + ch)*H_ + y)*W_ + xc];
    }
    __syncthreads();
    for (int idx = t; idx < 56 * 32; idx += 256) {
        const int xc = idx >> 5, chp = idx & 31;
        const float v0 = xs[2*chp][xc], v1 = xs[2*chp + 1][xc];
        const unsigned short h0 = f2bf(v0), h1 = f2bf(v1);
        const unsigned short l0 = f2bf(v0 - bf2f(h0));
        const unsigned short l1 = f2bf(v1 - bf2f(h1));
        const size_t o = ((size_t)(b*58 + y + 1) * 64 + (xc + 1)) * 256 + c0 + 2*chp;
        *(unsigned*)(xhi + o) = (unsigned)h0 | ((unsigned)h1 << 16);
        *(unsigned*)(xlo + o) = (unsigned)l0 | ((unsigned)l1 << 16);
    }
}

// ---------------------------------------------------------------------------
// Kernel 1b: weights -> Af_hi/Af_lo FRAGMENT order (R4).
// ---------------------------------------------------------------------------
__global__ __launch_bounds__(256) void prep_w(
    const float* __restrict__ wq, const float* __restrict__ wk,
    const float* __restrict__ wv,
    unsigned short* __restrict__ Ahi, unsigned short* __restrict__ Alo)
{
    const int g = blockIdx.x * 256 + threadIdx.x;
    if (g >= 320 * 2304) return;
    const int m = g / 2304, k = g - m * 2304;
    const int s = k >> 8, c = k & 255;
    float w;
    if (m < 32)      w = wq[((size_t)m*C_ + c)*9 + s];
    else if (m < 64) w = wk[((size_t)(m-32)*C_ + c)*9 + s];
    else             w = wv[((size_t)(m-64)*C_ + c)*9 + s];
    const unsigned short h = f2bf(w);
    // fragment-order: [m>>4][s][cc][quad*16 + (m&15)][e]
    const int cc = (k >> 5) & 7, quad = (k >> 3) & 3, e = k & 7;
    const size_t o = ((((size_t)(m >> 4)*9 + s)*8 + cc)*64 + (quad*16 + (m & 15)))*8 + e;
    Ahi[o] = h;
    Alo[o] = f2bf(w - bf2f(h));
}

// ---------------------------------------------------------------------------
// Kernel 2: FUSED conv (R2 structure, reverted from R3's regression).
// grid (b 8, y 56, z 5), block 256 = 4 waves.
//   z == 4      -> q/k conv (hi/lo 3-MFMA)
//   z in 0..3   -> v conv (plain bf16), mg = z, 64 channels, full 56-px row
// R4 changes vs R2: (1) A-loads are dense 1KB bursts (Af layout);
// (2) v epilogue does LDS-transpose then wave-partitioned dense short8
//     Vf stores (R2 scattered 2B scalars -> TA serialization + write-amp).
// ---------------------------------------------------------------------------
__global__ __launch_bounds__(256) void conv_fused(
    const unsigned short* __restrict__ xhi, const unsigned short* __restrict__ xlo,
    const unsigned short* __restrict__ Ahi, const unsigned short* __restrict__ Alo,
    const float* __restrict__ bq, const float* __restrict__ bk,
    const float* __restrict__ bv,
    unsigned short* __restrict__ qkt_hi, unsigned short* __restrict__ qkt_lo,
    unsigned short* __restrict__ vbf)
{
    __shared__ uint4 sH[3*64*4 + 8];   // +8 pad: col+dx can run to 65 (px>=56 discarded)
    __shared__ uint4 sL[3*64*4 + 8];   // only used by qk path
    const int b = blockIdx.x, y = blockIdx.y, z = blockIdx.z;
    const int t = threadIdx.x;
    const int w = t >> 6, L = t & 63;
    const int ln = L & 15, quad = L >> 4;

    if (z == 4) {
        // ---------------- q/k path (hi/lo 3-MFMA) ----------------
        f32x4 acc[4];
#pragma unroll
        for (int nt = 0; nt < 4; nt++) acc[nt] = (f32x4)0.0f;

        uint4 ph[3], pl[3];
#pragma unroll
        for (int i = 0; i < 3; i++) {
            const int idx = t + i*256;
            const int r = idx >> 8, col = (idx >> 2) & 63, c8 = idx & 3;
            const size_t go = ((size_t)((b*58 + y + r)*64 + col))*256 + c8*8;
            ph[i] = *(const uint4*)(xhi + go);
            pl[i] = *(const uint4*)(xlo + go);
        }

        for (int cc = 0; cc < 8; cc++) {
            __syncthreads();
#pragma unroll
            for (int i = 0; i < 3; i++) {
                const int idx = t + i*256;
                const int r = idx >> 8, col = (idx >> 2) & 63, c8 = idx & 3;
                sH[SWZ(r, col, c8)] = ph[i];
                sL[SWZ(r, col, c8)] = pl[i];
            }
            __syncthreads();
            if (cc < 7) {
#pragma unroll
                for (int i = 0; i < 3; i++) {
                    const int idx = t + i*256;
                    const int r = idx >> 8, col = (idx >> 2) & 63, c8 = idx & 3;
                    const size_t go = ((size_t)((b*58 + y + r)*64 + col))*256 + (cc+1)*32 + c8*8;
                    ph[i] = *(const uint4*)(xhi + go);
                    pl[i] = *(const uint4*)(xlo + go);
                }
            }
#pragma unroll
            for (int s = 0; s < 9; s++) {
                const int dy = s / 3 - 1, dx = s % 3 - 1;
                // dense A-frag burst: rowgrp = w
                const size_t aoff = (((size_t)(w*9 + s)*8 + cc)*64 + L)*8;
                const short8 ah = *(const short8*)(Ahi + aoff);
                const short8 al = *(const short8*)(Alo + aoff);
                const int r = dy + 1;
#pragma unroll
                for (int nt = 0; nt < 4; nt++) {
                    const int col = nt*16 + ln + dx + 1;
                    const int i4 = SWZ(r, col, quad);
                    const short8 bh = *(const short8*)&sH[i4];
                    const short8 bl = *(const short8*)&sL[i4];
                    acc[nt] = MFMA16(ah, bh, acc[nt]);
                    acc[nt] = MFMA16(ah, bl, acc[nt]);
                    acc[nt] = MFMA16(al, bh, acc[nt]);
                }
            }
        }

        // epilogue: fragment-order Qf/Kf writes (u16x4, 512B/wave dense)
#pragma unroll
        for (int nt = 0; nt < 4; nt++) {
            const int px = nt*16 + ln;
            if (px >= 56) continue;
            const int pix = y*56 + px;
            u16x4 hi4, lo4;
#pragma unroll
            for (int r = 0; r < 4; r++) {
                const int m = w*16 + quad*4 + r;
                const float bias = (m < 32) ? bq[m] : bk[m - 32];
                const float val = acc[nt][r] + bias;
                const unsigned short h = f2bf(val);
                hi4[r] = h;
                lo4[r] = f2bf(val - bf2f(h));
            }
            const int m0 = w*16 + quad*4;
            size_t o;
            if (w < 2) {
                o = ((size_t)(b*196 + (pix >> 4))*64 + (m0 >> 3)*16 + (pix & 15))*8 + (m0 & 7);
            } else {
                const int mk0 = m0 - 32;
                o = (size_t)QF_ELEMS +
                    (((size_t)(b*49 + (pix >> 6))*4 + ((pix >> 4) & 3))*64
                     + (mk0 >> 3)*16 + (pix & 15))*8 + (mk0 & 7);
            }
            *(u16x4*)(qkt_hi + o) = hi4;
            *(u16x4*)(qkt_lo + o) = lo4;
        }
    } else {
        // ---------------- v path (plain bf16), 64 channels ----------------
        const int mg = z;

        f32x4 acc[4];
#pragma unroll
        for (int nt = 0; nt < 4; nt++) acc[nt] = (f32x4)0.0f;

        uint4 ph[3];
#pragma unroll
        for (int i = 0; i < 3; i++) {
            const int idx = t + i*256;
            const int r = idx >> 8, col = (idx >> 2) & 63, c8 = idx & 3;
            const size_t go = ((size_t)((b*58 + y + r)*64 + col))*256 + c8*8;
            ph[i] = *(const uint4*)(xhi + go);
        }

        for (int cc = 0; cc < 8; cc++) {
            __syncthreads();
#pragma unroll
            for (int i = 0; i < 3; i++) {
                const int idx = t + i*256;
                const int r = idx >> 8, col = (idx >> 2) & 63, c8 = idx & 3;
                sH[SWZ(r, col, c8)] = ph[i];
            }
            __syncthreads();
            if (cc < 7) {
#pragma unroll
                for (int i = 0; i < 3; i++) {
                    const int idx = t + i*256;
                    const int r = idx >> 8, col = (idx >> 2) & 63, c8 = idx & 3;
                    const size_t go = ((size_t)((b*58 + y + r)*64 + col))*256 + (cc+1)*32 + c8*8;
                    ph[i] = *(const uint4*)(xhi + go);
                }
            }
#pragma unroll
            for (int s = 0; s < 9; s++) {
                const int dy = s / 3 - 1, dx = s % 3 - 1;
                // dense A-frag burst: rowgrp = 4 + mg*4 + w
                const size_t aoff = (((size_t)((4 + mg*4 + w)*9 + s)*8 + cc)*64 + L)*8;
                const short8 a = *(const short8*)(Ahi + aoff);
                const int r = dy + 1;
#pragma unroll
                for (int nt = 0; nt < 4; nt++) {
                    const int col = nt*16 + ln + dx + 1;
                    const short8 bf = *(const short8*)&sH[SWZ(r, col, quad)];
                    acc[nt] = MFMA16(a, bf, acc[nt]);
                }
            }
        }

        // ---- epilogue R4: LDS transpose -> wave-partitioned dense Vf ----
        __syncthreads();   // all waves done reading sH
        unsigned short* Vs = (unsigned short*)sH;   // [64][VSTR] = 7.4KB
#pragma unroll
        for (int nt = 0; nt < 4; nt++) {
            const int px = nt*16 + ln;
            if (px >= 56) continue;
#pragma unroll
            for (int r = 0; r < 4; r++) {
                const int cl = w*16 + quad*4 + r;     // local channel 0..63
                Vs[cl*VSTR + px] = f2bf(acc[nt][r] + bv[mg*64 + cl]);
            }
        }
        __syncthreads();
        // readback: wave w -> cgl = w&1, g-parity = w>>1 (full cover, no dup)
        const int p0 = y*56;
        const int hh = L >> 5, c31 = L & 31;
        const int cgl = w & 1;
        const int cg = mg*2 + cgl;
        const int gend = (p0 + 55) >> 4;
        for (int g = (p0 >> 4) + (w >> 1); g <= gend; g += 2) {
            const int pxl0 = g*16 + hh*8 - p0;
            if (pxl0 >= 0 && pxl0 + 8 <= 56) {
                const short8 vv = *(const short8*)&Vs[(cgl*32 + c31)*VSTR + pxl0];
                const size_t o = ((((size_t)(b*8 + cg)*49 + (g >> 2))*4 + (g & 3))*64 + L)*8;
                *(short8*)(vbf + o) = vv;
            }
        }
    }
}

// ---------------------------------------------------------------------------
// Kernel 3: fused flash attention, 2-wave blocks (i-tile 32). Unchanged (R2).
// ---------------------------------------------------------------------------
__global__ __launch_bounds__(128, 4) void attn_flash2w(
    const unsigned short* __restrict__ qkt_hi, const unsigned short* __restrict__ qkt_lo,
    const unsigned short* __restrict__ vbf,
    unsigned short* __restrict__ op0, unsigned short* __restrict__ op1,
    float* __restrict__ mlbase)
{
    __shared__ unsigned short P[2][32*PSTR];   // 9.5 KB
    __shared__ float alphaL[2][32];

    const int bx = blockIdx.x;
    const int b = bx & 7, it = bx >> 3;
    const int chalf = blockIdx.y;
    const int jh = blockIdx.z;
    const int jt0 = jh * 25, njt = 25 - jh;    // 25 / 24 tiles
    const int i_base = it * 32;
    const int t = threadIdx.x;
    const int w = t >> 6, L = t & 63;
    const int ln = L & 15, quad = L >> 4;
    const int l32 = L & 31, h32 = L >> 5;

    const unsigned short* Kf_hi = qkt_hi + QF_ELEMS;
    const unsigned short* Kf_lo = qkt_lo + QF_ELEMS;

    const size_t qoff = ((size_t)(b*196 + it*2 + w)*64 + L)*8;
    const short8 qh = *(const short8*)(qkt_hi + qoff);
    const short8 ql = *(const short8*)(qkt_lo + qoff);

    float m_run = -INFINITY, l_run = 0.0f;
    f32x16 O0 = (f32x16)0.0f, O1 = (f32x16)0.0f;
    const int cg0 = chalf*4 + w*2;
    const unsigned short* vt0 = vbf + ((size_t)(b*8 + cg0)*49)*2048 + (size_t)L*8;
    const unsigned short* vt1 = vbf + ((size_t)(b*8 + cg0 + 1)*49)*2048 + (size_t)L*8;
    const unsigned short* kbh = Kf_hi + (size_t)b*49*2048 + (size_t)L*8;
    const unsigned short* kbl = Kf_lo + (size_t)b*49*2048 + (size_t)L*8;

    for (int jtl = 0; jtl < njt; jtl++) {
        const int jt = jt0 + jtl;
        const int buf = jtl & 1;

        short8 Va[4], Vb[4];
#pragma unroll
        for (int s = 0; s < 4; s++) {
            Va[s] = *(const short8*)(vt0 + jt*2048 + s*512);
            Vb[s] = *(const short8*)(vt1 + jt*2048 + s*512);
        }

        f32x4 sacc[4];
#pragma unroll
        for (int tj = 0; tj < 4; tj++) {
            const short8 kh = *(const short8*)(kbh + jt*2048 + tj*512);
            const short8 kl = *(const short8*)(kbl + jt*2048 + tj*512);
            f32x4 a = (f32x4)0.0f;
            a = MFMA16(kh, qh, a);
            a = MFMA16(kh, ql, a);
            a = MFMA16(kl, qh, a);
            sacc[tj] = a;
        }
        float mt0 = fmaxf(fmaxf(sacc[0][0], sacc[0][1]), fmaxf(sacc[0][2], sacc[0][3]));
        float mt1 = fmaxf(fmaxf(sacc[1][0], sacc[1][1]), fmaxf(sacc[1][2], sacc[1][3]));
        float mt2 = fmaxf(fmaxf(sacc[2][0], sacc[2][1]), fmaxf(sacc[2][2], sacc[2][3]));
        float mt3 = fmaxf(fmaxf(sacc[3][0], sacc[3][1]), fmaxf(sacc[3][2], sacc[3][3]));
        float mx = fmaxf(fmaxf(mt0, mt1), fmaxf(mt2, mt3));
        mx = fmaxf(mx, __shfl_xor(mx, 16));
        mx = fmaxf(mx, __shfl_xor(mx, 32));
        const float m_new = fmaxf(m_run, mx);
        const float alpha = __expf(m_run - m_new);
        m_run = m_new;

#pragma unroll
        for (int tj = 0; tj < 4; tj++)
#pragma unroll
            for (int r = 0; r < 4; r++)
                sacc[tj][r] = __expf(sacc[tj][r] - m_new);
        float s0 = (sacc[0][0] + sacc[0][1]) + (sacc[0][2] + sacc[0][3]);
        float s1 = (sacc[1][0] + sacc[1][1]) + (sacc[1][2] + sacc[1][3]);
        float s2 = (sacc[2][0] + sacc[2][1]) + (sacc[2][2] + sacc[2][3]);
        float s3 = (sacc[3][0] + sacc[3][1]) + (sacc[3][2] + sacc[3][3]);
        float ps = (s0 + s1) + (s2 + s3);
        ps += __shfl_xor(ps, 16);
        ps += __shfl_xor(ps, 32);
        l_run = l_run * alpha + ps;

        {
            unsigned short* prow = &P[buf][(w*16 + ln)*PSTR];
#pragma unroll
            for (int tj = 0; tj < 4; tj++) {
                u16x4 pk;
#pragma unroll
                for (int r = 0; r < 4; r++) pk[r] = f2bf(sacc[tj][r]);
                *(u16x4*)(prow + tj*16 + quad*4) = pk;
            }
        }
        if (quad == 0) alphaL[buf][w*16 + ln] = alpha;

        __syncthreads();

        const float a = alphaL[buf][l32];
        if (__any(a != 1.0f)) {
#pragma unroll
            for (int rg = 0; rg < 16; rg++) { O0[rg] *= a; O1[rg] *= a; }
        }
        short8 Bp[4];
#pragma unroll
        for (int s = 0; s < 4; s++) {
            Bp[s] = *(const short8*)&P[buf][l32*PSTR + s*16 + h32*8];
            O0 = MFMA32(Va[s], Bp[s], O0);
        }
#pragma unroll
        for (int s = 0; s < 4; s++)
            O1 = MFMA32(Vb[s], Bp[s], O1);
    }

    if (chalf == 0 && quad == 0) {
        const int i = i_base + w*16 + ln;
        mlbase[jh*BN_ + b*N_ + i]       = m_run;
        mlbase[(2 + jh)*BN_ + b*N_ + i] = l_run;
    }
    unsigned short* OP = jh ? op1 : op0;
    const int pix = i_base + l32;
#pragma unroll
    for (int g = 0; g < 2; g++) {
        const f32x16 Ot = g ? O1 : O0;
        const int cg = chalf*128 + w*64 + g*32;
#pragma unroll
        for (int reg = 0; reg < 16; reg++) {
            const int c = cg + (reg & 3) + 8*(reg >> 2) + 4*h32;
            OP[(size_t)(b*C_ + c)*N_ + pix] = f2bf(Ot[reg]);
        }
    }
}

// ---------------------------------------------------------------------------
// Kernel 4: combine the two j-half partials + residual. Unchanged.
// ---------------------------------------------------------------------------
__global__ __launch_bounds__(256) void combine(
    const unsigned short* __restrict__ op0, const unsigned short* __restrict__ op1,
    const float* __restrict__ mlbase,
    const float* __restrict__ x, const float* __restrict__ gptr,
    float* __restrict__ out)
{
    const int bid = blockIdx.x;
    const int b = bid / 49, pt = bid - b*49;
    const int ch2 = blockIdx.y;
    const int t = threadIdx.x;
    const int pix = pt*64 + (t & 63);
    const int cofs = t >> 6;

    const float m0 = mlbase[b*N_ + pix];
    const float m1 = mlbase[BN_ + b*N_ + pix];
    const float l0 = mlbase[2*BN_ + b*N_ + pix];
    const float l1 = mlbase[3*BN_ + b*N_ + pix];
    const float mm = fmaxf(m0, m1);
    const float a0 = __expf(m0 - mm), a1 = __expf(m1 - mm);
    const float gamma = gptr[0];
    const float inv = gamma / (a0*l0 + a1*l1);
    const float c0 = a0 * inv, c1 = a1 * inv;

    for (int ci = 0; ci < 32; ci++) {
        const int c = ch2*128 + cofs + ci*4;
        const size_t idx = (size_t)(b*C_ + c)*N_ + pix;
        const float o = c0 * bf2f(op0[idx]) + c1 * bf2f(op1[idx]);
        out[idx] = x[idx] + o;
    }
}

// ---------------------------------------------------------------------------
extern "C" void kernel_launch(void* const* d_in, const int* in_sizes, int n_in,
                              void* d_out, int out_size, void* d_ws, size_t ws_size,
                              hipStream_t stream)
{
    (void)in_sizes; (void)n_in; (void)out_size; (void)ws_size;
    const float* x  = (const float*)d_in[0];
    const float* wq = (const float*)d_in[1];
    const float* bq = (const float*)d_in[2];
    const float* wk = (const float*)d_in[3];
    const float* bk = (const float*)d_in[4];
    const float* wv = (const float*)d_in[5];
    const float* bv = (const float*)d_in[6];
    const float* gm = (const float*)d_in[7];
    float* out = (float*)d_out;

    unsigned short* u = (unsigned short*)d_ws;
    unsigned short* xhi = u;                      // conv input; later O-partial jh=0
    unsigned short* xlo = u + XT_ELEMS;           // conv input; later O-partial jh=1
    unsigned short* Ahi = u + AHI_OFF;            // Af weights; first 400KB later m/l
    unsigned short* Alo = u + ALO_OFF;
    unsigned short* qkt_hi = u + QKT_HI_OFF;      // [Qf_hi | Kf_hi] fragment-order
    unsigned short* qkt_lo = u + QKT_LO_OFF;      // [Qf_lo | Kf_lo]
    unsigned short* vbf = u + VBF_OFF;            // Vf fragment-order
    float* mlbase = (float*)Ahi;                  // 4 * B*N floats = 401 KB

    hipLaunchKernelGGL(zero_pads, dim3(1024), dim3(256), 0, stream,
                       (uint4*)d_ws, (2*XT_ELEMS*2)/16);
    hipLaunchKernelGGL(prep_x, dim3(4, 56, 8), dim3(256), 0, stream, x, xhi, xlo);
    hipLaunchKernelGGL(prep_w, dim3(2880), dim3(256), 0, stream, wq, wk, wv, Ahi, Alo);
    hipLaunchKernelGGL(conv_fused, dim3(8, 56, 5), dim3(256), 0, stream,
                       xhi, xlo, Ahi, Alo, bq, bk, bv, qkt_hi, qkt_lo, vbf);
    hipLaunchKernelGGL(attn_flash2w, dim3(98*8, 2, 2), dim3(128), 0, stream,
                       qkt_hi, qkt_lo, vbf, xhi, xlo, mlbase);
    hipLaunchKernelGGL(combine, dim3(392, 2), dim3(256), 0, stream,
                       xhi, xlo, mlbase, x, gm, out);
}

// Round 5
// 332.735 us; speedup vs baseline: 1.2921x; 1.0310x over previous
//
#include <hip/hip_runtime.h>
#include <math.h>

// Problem constants
#define B_ 8
#define C_ 256
#define H_ 56
#define W_ 56
#define N_ 3136  // 56*56 = 49*64
#define BN_ (B_*N_)

typedef __attribute__((ext_vector_type(8))) short short8;
typedef __attribute__((ext_vector_type(4))) float f32x4;
typedef __attribute__((ext_vector_type(16))) float f32x16;
typedef __attribute__((ext_vector_type(4))) unsigned short u16x4;
#define MFMA16(A, Bf, Cf) __builtin_amdgcn_mfma_f32_16x16x32_bf16((A), (Bf), (Cf), 0, 0, 0)
#define MFMA32(A, Bf, Cf) __builtin_amdgcn_mfma_f32_32x32x16_bf16((A), (Bf), (Cf), 0, 0, 0)

// -------------------- workspace layout (ushort units) --------------------
#define XT_ELEMS (B_*58*64*256)           // 7,602,176
#define A_ELEMS  (320*2304)               // 737,280
#define AHI_OFF  (2*XT_ELEMS)
#define ALO_OFF  (AHI_OFF + A_ELEMS)
#define QKT_HI_OFF (ALO_OFF + A_ELEMS)
#define QKT_ELEMS  (B_*N_*64)             // 1,605,632 = QF_ELEMS + KF_ELEMS
#define QKT_LO_OFF (QKT_HI_OFF + QKT_ELEMS)
#define VBF_OFF    (QKT_LO_OFF + QKT_ELEMS)
#define VBF_ELEMS  (B_*C_*N_)             // 6,422,528

// Fragment-order layouts: attn lane L reads base + L*16B.
// Qf: [b][q16 (pix>>4, 196)][fq*16 + ln (64)][8]   (features 0..31)
// Kf: [b][jt (49)][tj (4)][fq*16 + ln (64)][8]     (features 32..63)
// Vf: [b][cg (8)][jt (49)][s (4)][hh*32 + c31 (64)][8]
#define QF_ELEMS (B_*196*64*8)            // 802,816

// Af fragment-order weights: [rowgrp 20][s 9][cc 8][L 64][8]
// rowgrp = m>>4 (qk rows 0..63 -> g 0..3; v rows 64..319 -> g 4..19).

// LDS swizzle for conv B-slabs: chunk (r,col,c8) -> uint4 index
#define SWZ(r, col, c8) ((((r)*64 + (col))*4) + ((c8) ^ ((col) & 3)))

// P LDS row stride (ushorts) for attn
#define PSTR 76
// Vs (conv v-epilogue LDS transpose) pixel stride: 29 dwords, coprime 32 banks
#define VSTR 58

__device__ inline unsigned short f2bf(float f) {
    unsigned u = __float_as_uint(f);
    unsigned r = (u + 0x7fffu + ((u >> 16) & 1u)) >> 16;   // RNE
    return (unsigned short)r;
}
__device__ inline float bf2f(unsigned short h) {
    return __uint_as_float(((unsigned)h) << 16);
}

// ---------------------------------------------------------------------------
// Kernel 0: zero the padded x regions.
// ---------------------------------------------------------------------------
__global__ __launch_bounds__(256) void zero_pads(uint4* __restrict__ p, int n16)
{
    const int stride = gridDim.x * 256;
    for (int i = blockIdx.x * 256 + threadIdx.x; i < n16; i += stride)
        p[i] = make_uint4(0, 0, 0, 0);
}

// ---------------------------------------------------------------------------
// Kernel 1a: x (fp32 NCHW) -> padded pixel-major bf16 hi/lo.
// ---------------------------------------------------------------------------
__global__ __launch_bounds__(256) void prep_x(
    const float* __restrict__ x,
    unsigned short* __restrict__ xhi, unsigned short* __restrict__ xlo)
{
    __shared__ float xs[64][57];
    const int cc = blockIdx.x, y = blockIdx.y, b = blockIdx.z;
    const int t = threadIdx.x;
    const int c0 = cc * 64;
    for (int idx = t; idx < 64 * 56; idx += 256) {
        const int ch = idx / 56, xc = idx - ch * 56;
        xs[ch][xc] = x[((size_t)(b*C_ + c0 + ch)*H_ + y)*W_ + xc];
    }
    __syncthreads();
    for (int idx = t; idx < 56 * 32; idx += 256) {
        const int xc = idx >> 5, chp = idx & 31;
        const float v0 = xs[2*chp][xc], v1 = xs[2*chp + 1][xc];
        const unsigned short h0 = f2bf(v0), h1 = f2bf(v1);
        const unsigned short l0 = f2bf(v0 - bf2f(h0));
        const unsigned short l1 = f2bf(v1 - bf2f(h1));
        const size_t o = ((size_t)(b*58 + y + 1) * 64 + (xc + 1)) * 256 + c0 + 2*chp;
        *(unsigned*)(xhi + o) = (unsigned)h0 | ((unsigned)h1 << 16);
        *(unsigned*)(xlo + o) = (unsigned)l0 | ((unsigned)l1 << 16);
    }
}

// ---------------------------------------------------------------------------
// Kernel 1b: weights -> Af_hi/Af_lo FRAGMENT order.
// ---------------------------------------------------------------------------
__global__ __launch_bounds__(256) void prep_w(
    const float* __restrict__ wq, const float* __restrict__ wk,
    const float* __restrict__ wv,
    unsigned short* __restrict__ Ahi, unsigned short* __restrict__ Alo)
{
    const int g = blockIdx.x * 256 + threadIdx.x;
    if (g >= 320 * 2304) return;
    const int m = g / 2304, k = g - m * 2304;
    const int s = k >> 8, c = k & 255;
    float w;
    if (m < 32)      w = wq[((size_t)m*C_ + c)*9 + s];
    else if (m < 64) w = wk[((size_t)(m-32)*C_ + c)*9 + s];
    else             w = wv[((size_t)(m-64)*C_ + c)*9 + s];
    const unsigned short h = f2bf(w);
    // fragment-order: [m>>4][s][cc][quad*16 + (m&15)][e]
    const int cc = (k >> 5) & 7, quad = (k >> 3) & 3, e = k & 7;
    const size_t o = ((((size_t)(m >> 4)*9 + s)*8 + cc)*64 + (quad*16 + (m & 15)))*8 + e;
    Ahi[o] = h;
    Alo[o] = f2bf(w - bf2f(h));
}

// ---------------------------------------------------------------------------
// Kernel 2: FUSED conv. grid (b 8, y 56, z 3), block 256 = 4 waves.
//   z == 0      -> q/k conv (hi/lo 3-MFMA), 4 waves x 1 row-group
//   z in 1..2   -> v conv, 128 channels: 4 waves x 2 ROW-GROUPS (R5 change)
// R5: v-path A-side blocking. R4 counters showed conv is LDS-BW-bound
// (~3.5GB LDS traffic, 1 MFMA per 1KB B-read in v path; all other pipes
// <30%). Two row-groups per wave -> 2 MFMAs per B-read, halving v LDS
// reads, staging writes, and v x-fetch.
// ---------------------------------------------------------------------------
__global__ __launch_bounds__(256) void conv_fused(
    const unsigned short* __restrict__ xhi, const unsigned short* __restrict__ xlo,
    const unsigned short* __restrict__ Ahi, const unsigned short* __restrict__ Alo,
    const float* __restrict__ bq, const float* __restrict__ bk,
    const float* __restrict__ bv,
    unsigned short* __restrict__ qkt_hi, unsigned short* __restrict__ qkt_lo,
    unsigned short* __restrict__ vbf)
{
    __shared__ uint4 SMEM[1552];       // 24.8 KB: sH | sL (qk) ; Vs overlay (v)
    uint4* sH = SMEM;
    uint4* sL = SMEM + 776;
    const int b = blockIdx.x, y = blockIdx.y, z = blockIdx.z;
    const int t = threadIdx.x;
    const int w = t >> 6, L = t & 63;
    const int ln = L & 15, quad = L >> 4;

    if (z == 0) {
        // ---------------- q/k path (hi/lo 3-MFMA) ----------------
        f32x4 acc[4];
#pragma unroll
        for (int nt = 0; nt < 4; nt++) acc[nt] = (f32x4)0.0f;

        uint4 ph[3], pl[3];
#pragma unroll
        for (int i = 0; i < 3; i++) {
            const int idx = t + i*256;
            const int r = idx >> 8, col = (idx >> 2) & 63, c8 = idx & 3;
            const size_t go = ((size_t)((b*58 + y + r)*64 + col))*256 + c8*8;
            ph[i] = *(const uint4*)(xhi + go);
            pl[i] = *(const uint4*)(xlo + go);
        }

        for (int cc = 0; cc < 8; cc++) {
            __syncthreads();
#pragma unroll
            for (int i = 0; i < 3; i++) {
                const int idx = t + i*256;
                const int r = idx >> 8, col = (idx >> 2) & 63, c8 = idx & 3;
                sH[SWZ(r, col, c8)] = ph[i];
                sL[SWZ(r, col, c8)] = pl[i];
            }
            __syncthreads();
            if (cc < 7) {
#pragma unroll
                for (int i = 0; i < 3; i++) {
                    const int idx = t + i*256;
                    const int r = idx >> 8, col = (idx >> 2) & 63, c8 = idx & 3;
                    const size_t go = ((size_t)((b*58 + y + r)*64 + col))*256 + (cc+1)*32 + c8*8;
                    ph[i] = *(const uint4*)(xhi + go);
                    pl[i] = *(const uint4*)(xlo + go);
                }
            }
#pragma unroll
            for (int s = 0; s < 9; s++) {
                const int dx = s % 3 - 1;
                const int r = s / 3;
                // dense A-frag burst: rowgrp = w
                const size_t aoff = (((size_t)(w*9 + s)*8 + cc)*64 + L)*8;
                const short8 ah = *(const short8*)(Ahi + aoff);
                const short8 al = *(const short8*)(Alo + aoff);
#pragma unroll
                for (int nt = 0; nt < 4; nt++) {
                    const int col = nt*16 + ln + dx + 1;
                    const int i4 = SWZ(r, col, quad);
                    const short8 bh = *(const short8*)&sH[i4];
                    const short8 bl = *(const short8*)&sL[i4];
                    acc[nt] = MFMA16(ah, bh, acc[nt]);
                    acc[nt] = MFMA16(ah, bl, acc[nt]);
                    acc[nt] = MFMA16(al, bh, acc[nt]);
                }
            }
        }

        // epilogue: fragment-order Qf/Kf writes
#pragma unroll
        for (int nt = 0; nt < 4; nt++) {
            const int px = nt*16 + ln;
            if (px >= 56) continue;
            const int pix = y*56 + px;
            u16x4 hi4, lo4;
#pragma unroll
            for (int r = 0; r < 4; r++) {
                const int m = w*16 + quad*4 + r;
                const float bias = (m < 32) ? bq[m] : bk[m - 32];
                const float val = acc[nt][r] + bias;
                const unsigned short h = f2bf(val);
                hi4[r] = h;
                lo4[r] = f2bf(val - bf2f(h));
            }
            const int m0 = w*16 + quad*4;
            size_t o;
            if (w < 2) {
                o = ((size_t)(b*196 + (pix >> 4))*64 + (m0 >> 3)*16 + (pix & 15))*8 + (m0 & 7);
            } else {
                const int mk0 = m0 - 32;
                o = (size_t)QF_ELEMS +
                    (((size_t)(b*49 + (pix >> 6))*4 + ((pix >> 4) & 3))*64
                     + (mk0 >> 3)*16 + (pix & 15))*8 + (mk0 & 7);
            }
            *(u16x4*)(qkt_hi + o) = hi4;
            *(u16x4*)(qkt_lo + o) = lo4;
        }
    } else {
        // ------- v path: 128 channels, 2 row-groups per wave (R5) -------
        const int mg = z - 1;              // 0 or 1

        f32x4 acc[2][4];
#pragma unroll
        for (int g2 = 0; g2 < 2; g2++)
#pragma unroll
            for (int nt = 0; nt < 4; nt++) acc[g2][nt] = (f32x4)0.0f;

        uint4 ph[3];
#pragma unroll
        for (int i = 0; i < 3; i++) {
            const int idx = t + i*256;
            const int r = idx >> 8, col = (idx >> 2) & 63, c8 = idx & 3;
            const size_t go = ((size_t)((b*58 + y + r)*64 + col))*256 + c8*8;
            ph[i] = *(const uint4*)(xhi + go);
        }

        for (int cc = 0; cc < 8; cc++) {
            __syncthreads();
#pragma unroll
            for (int i = 0; i < 3; i++) {
                const int idx = t + i*256;
                const int r = idx >> 8, col = (idx >> 2) & 63, c8 = idx & 3;
                sH[SWZ(r, col, c8)] = ph[i];
            }
            __syncthreads();
            if (cc < 7) {
#pragma unroll
                for (int i = 0; i < 3; i++) {
                    const int idx = t + i*256;
                    const int r = idx >> 8, col = (idx >> 2) & 63, c8 = idx & 3;
                    const size_t go = ((size_t)((b*58 + y + r)*64 + col))*256 + (cc+1)*32 + c8*8;
                    ph[i] = *(const uint4*)(xhi + go);
                }
            }
#pragma unroll
            for (int s = 0; s < 9; s++) {
                const int dx = s % 3 - 1;
                const int r = s / 3;
                // dense A-frag bursts: rowgrps 4 + mg*8 + w*2 + {0,1}
                const size_t a0off = (((size_t)((4 + mg*8 + w*2)*9 + s)*8 + cc)*64 + L)*8;
                const short8 a0 = *(const short8*)(Ahi + a0off);
                const short8 a1 = *(const short8*)(Ahi + a0off + 9*8*64*8);
#pragma unroll
                for (int nt = 0; nt < 4; nt++) {
                    const int col = nt*16 + ln + dx + 1;
                    const short8 bf = *(const short8*)&sH[SWZ(r, col, quad)];
                    acc[0][nt] = MFMA16(a0, bf, acc[0][nt]);
                    acc[1][nt] = MFMA16(a1, bf, acc[1][nt]);
                }
            }
        }

        // ---- epilogue: LDS transpose (128ch x 56px) -> dense Vf tiles ----
        __syncthreads();   // all waves done reading sH
        unsigned short* Vs = (unsigned short*)SMEM;   // [128][VSTR] = 14.8 KB
#pragma unroll
        for (int g2 = 0; g2 < 2; g2++)
#pragma unroll
            for (int nt = 0; nt < 4; nt++) {
                const int px = nt*16 + ln;
                if (px >= 56) continue;
#pragma unroll
                for (int r = 0; r < 4; r++) {
                    const int cl = (w*2 + g2)*16 + quad*4 + r;   // local ch 0..127
                    Vs[cl*VSTR + px] = f2bf(acc[g2][nt][r] + bv[mg*128 + cl]);
                }
            }
        __syncthreads();
        // readback: wave w owns 32-channel group cg = mg*4 + w
        const int p0 = y*56;
        const int hh = L >> 5, c31 = L & 31;
        const int cg = mg*4 + w;
        const int gend = (p0 + 55) >> 4;
        for (int gi = p0 >> 4; gi <= gend; gi++) {
            const int pxl0 = gi*16 + hh*8 - p0;
            if (pxl0 >= 0 && pxl0 + 8 <= 56) {
                const short8 vv = *(const short8*)&Vs[(w*32 + c31)*VSTR + pxl0];
                const size_t o = ((((size_t)(b*8 + cg)*49 + (gi >> 2))*4 + (gi & 3))*64 + L)*8;
                *(short8*)(vbf + o) = vv;
            }
        }
    }
}

// ---------------------------------------------------------------------------
// Kernel 3: fused flash attention, 2-wave blocks (i-tile 32). Unchanged.
// ---------------------------------------------------------------------------
__global__ __launch_bounds__(128, 4) void attn_flash2w(
    const unsigned short* __restrict__ qkt_hi, const unsigned short* __restrict__ qkt_lo,
    const unsigned short* __restrict__ vbf,
    unsigned short* __restrict__ op0, unsigned short* __restrict__ op1,
    float* __restrict__ mlbase)
{
    __shared__ unsigned short P[2][32*PSTR];   // 9.5 KB
    __shared__ float alphaL[2][32];

    const int bx = blockIdx.x;
    const int b = bx & 7, it = bx >> 3;
    const int chalf = blockIdx.y;
    const int jh = blockIdx.z;
    const int jt0 = jh * 25, njt = 25 - jh;    // 25 / 24 tiles
    const int i_base = it * 32;
    const int t = threadIdx.x;
    const int w = t >> 6, L = t & 63;
    const int ln = L & 15, quad = L >> 4;
    const int l32 = L & 31, h32 = L >> 5;

    const unsigned short* Kf_hi = qkt_hi + QF_ELEMS;
    const unsigned short* Kf_lo = qkt_lo + QF_ELEMS;

    const size_t qoff = ((size_t)(b*196 + it*2 + w)*64 + L)*8;
    const short8 qh = *(const short8*)(qkt_hi + qoff);
    const short8 ql = *(const short8*)(qkt_lo + qoff);

    float m_run = -INFINITY, l_run = 0.0f;
    f32x16 O0 = (f32x16)0.0f, O1 = (f32x16)0.0f;
    const int cg0 = chalf*4 + w*2;
    const unsigned short* vt0 = vbf + ((size_t)(b*8 + cg0)*49)*2048 + (size_t)L*8;
    const unsigned short* vt1 = vbf + ((size_t)(b*8 + cg0 + 1)*49)*2048 + (size_t)L*8;
    const unsigned short* kbh = Kf_hi + (size_t)b*49*2048 + (size_t)L*8;
    const unsigned short* kbl = Kf_lo + (size_t)b*49*2048 + (size_t)L*8;

    for (int jtl = 0; jtl < njt; jtl++) {
        const int jt = jt0 + jtl;
        const int buf = jtl & 1;

        short8 Va[4], Vb[4];
#pragma unroll
        for (int s = 0; s < 4; s++) {
            Va[s] = *(const short8*)(vt0 + jt*2048 + s*512);
            Vb[s] = *(const short8*)(vt1 + jt*2048 + s*512);
        }

        f32x4 sacc[4];
#pragma unroll
        for (int tj = 0; tj < 4; tj++) {
            const short8 kh = *(const short8*)(kbh + jt*2048 + tj*512);
            const short8 kl = *(const short8*)(kbl + jt*2048 + tj*512);
            f32x4 a = (f32x4)0.0f;
            a = MFMA16(kh, qh, a);
            a = MFMA16(kh, ql, a);
            a = MFMA16(kl, qh, a);
            sacc[tj] = a;
        }
        float mt0 = fmaxf(fmaxf(sacc[0][0], sacc[0][1]), fmaxf(sacc[0][2], sacc[0][3]));
        float mt1 = fmaxf(fmaxf(sacc[1][0], sacc[1][1]), fmaxf(sacc[1][2], sacc[1][3]));
        float mt2 = fmaxf(fmaxf(sacc[2][0], sacc[2][1]), fmaxf(sacc[2][2], sacc[2][3]));
        float mt3 = fmaxf(fmaxf(sacc[3][0], sacc[3][1]), fmaxf(sacc[3][2], sacc[3][3]));
        float mx = fmaxf(fmaxf(mt0, mt1), fmaxf(mt2, mt3));
        mx = fmaxf(mx, __shfl_xor(mx, 16));
        mx = fmaxf(mx, __shfl_xor(mx, 32));
        const float m_new = fmaxf(m_run, mx);
        const float alpha = __expf(m_run - m_new);
        m_run = m_new;

#pragma unroll
        for (int tj = 0; tj < 4; tj++)
#pragma unroll
            for (int r = 0; r < 4; r++)
                sacc[tj][r] = __expf(sacc[tj][r] - m_new);
        float s0 = (sacc[0][0] + sacc[0][1]) + (sacc[0][2] + sacc[0][3]);
        float s1 = (sacc[1][0] + sacc[1][1]) + (sacc[1][2] + sacc[1][3]);
        float s2 = (sacc[2][0] + sacc[2][1]) + (sacc[2][2] + sacc[2][3]);
        float s3 = (sacc[3][0] + sacc[3][1]) + (sacc[3][2] + sacc[3][3]);
        float ps = (s0 + s1) + (s2 + s3);
        ps += __shfl_xor(ps, 16);
        ps += __shfl_xor(ps, 32);
        l_run = l_run * alpha + ps;

        {
            unsigned short* prow = &P[buf][(w*16 + ln)*PSTR];
#pragma unroll
            for (int tj = 0; tj < 4; tj++) {
                u16x4 pk;
#pragma unroll
                for (int r = 0; r < 4; r++) pk[r] = f2bf(sacc[tj][r]);
                *(u16x4*)(prow + tj*16 + quad*4) = pk;
            }
        }
        if (quad == 0) alphaL[buf][w*16 + ln] = alpha;

        __syncthreads();

        const float a = alphaL[buf][l32];
        if (__any(a != 1.0f)) {
#pragma unroll
            for (int rg = 0; rg < 16; rg++) { O0[rg] *= a; O1[rg] *= a; }
        }
        short8 Bp[4];
#pragma unroll
        for (int s = 0; s < 4; s++) {
            Bp[s] = *(const short8*)&P[buf][l32*PSTR + s*16 + h32*8];
            O0 = MFMA32(Va[s], Bp[s], O0);
        }
#pragma unroll
        for (int s = 0; s < 4; s++)
            O1 = MFMA32(Vb[s], Bp[s], O1);
    }

    if (chalf == 0 && quad == 0) {
        const int i = i_base + w*16 + ln;
        mlbase[jh*BN_ + b*N_ + i]       = m_run;
        mlbase[(2 + jh)*BN_ + b*N_ + i] = l_run;
    }
    unsigned short* OP = jh ? op1 : op0;
    const int pix = i_base + l32;
#pragma unroll
    for (int g = 0; g < 2; g++) {
        const f32x16 Ot = g ? O1 : O0;
        const int cg = chalf*128 + w*64 + g*32;
#pragma unroll
        for (int reg = 0; reg < 16; reg++) {
            const int c = cg + (reg & 3) + 8*(reg >> 2) + 4*h32;
            OP[(size_t)(b*C_ + c)*N_ + pix] = f2bf(Ot[reg]);
        }
    }
}

// ---------------------------------------------------------------------------
// Kernel 4: combine the two j-half partials + residual. Unchanged.
// ---------------------------------------------------------------------------
__global__ __launch_bounds__(256) void combine(
    const unsigned short* __restrict__ op0, const unsigned short* __restrict__ op1,
    const float* __restrict__ mlbase,
    const float* __restrict__ x, const float* __restrict__ gptr,
    float* __restrict__ out)
{
    const int bid = blockIdx.x;
    const int b = bid / 49, pt = bid - b*49;
    const int ch2 = blockIdx.y;
    const int t = threadIdx.x;
    const int pix = pt*64 + (t & 63);
    const int cofs = t >> 6;

    const float m0 = mlbase[b*N_ + pix];
    const float m1 = mlbase[BN_ + b*N_ + pix];
    const float l0 = mlbase[2*BN_ + b*N_ + pix];
    const float l1 = mlbase[3*BN_ + b*N_ + pix];
    const float mm = fmaxf(m0, m1);
    const float a0 = __expf(m0 - mm), a1 = __expf(m1 - mm);
    const float gamma = gptr[0];
    const float inv = gamma / (a0*l0 + a1*l1);
    const float c0 = a0 * inv, c1 = a1 * inv;

    for (int ci = 0; ci < 32; ci++) {
        const int c = ch2*128 + cofs + ci*4;
        const size_t idx = (size_t)(b*C_ + c)*N_ + pix;
        const float o = c0 * bf2f(op0[idx]) + c1 * bf2f(op1[idx]);
        out[idx] = x[idx] + o;
    }
}

// ---------------------------------------------------------------------------
extern "C" void kernel_launch(void* const* d_in, const int* in_sizes, int n_in,
                              void* d_out, int out_size, void* d_ws, size_t ws_size,
                              hipStream_t stream)
{
    (void)in_sizes; (void)n_in; (void)out_size; (void)ws_size;
    const float* x  = (const float*)d_in[0];
    const float* wq = (const float*)d_in[1];
    const float* bq = (const float*)d_in[2];
    const float* wk = (const float*)d_in[3];
    const float* bk = (const float*)d_in[4];
    const float* wv = (const float*)d_in[5];
    const float* bv = (const float*)d_in[6];
    const float* gm = (const float*)d_in[7];
    float* out = (float*)d_out;

    unsigned short* u = (unsigned short*)d_ws;
    unsigned short* xhi = u;                      // conv input; later O-partial jh=0
    unsigned short* xlo = u + XT_ELEMS;           // conv input; later O-partial jh=1
    unsigned short* Ahi = u + AHI_OFF;            // Af weights; first 400KB later m/l
    unsigned short* Alo = u + ALO_OFF;
    unsigned short* qkt_hi = u + QKT_HI_OFF;      // [Qf_hi | Kf_hi] fragment-order
    unsigned short* qkt_lo = u + QKT_LO_OFF;      // [Qf_lo | Kf_lo]
    unsigned short* vbf = u + VBF_OFF;            // Vf fragment-order
    float* mlbase = (float*)Ahi;                  // 4 * B*N floats = 401 KB

    hipLaunchKernelGGL(zero_pads, dim3(1024), dim3(256), 0, stream,
                       (uint4*)d_ws, (2*XT_ELEMS*2)/16);
    hipLaunchKernelGGL(prep_x, dim3(4, 56, 8), dim3(256), 0, stream, x, xhi, xlo);
    hipLaunchKernelGGL(prep_w, dim3(2880), dim3(256), 0, stream, wq, wk, wv, Ahi, Alo);
    hipLaunchKernelGGL(conv_fused, dim3(8, 56, 3), dim3(256), 0, stream,
                       xhi, xlo, Ahi, Alo, bq, bk, bv, qkt_hi, qkt_lo, vbf);
    hipLaunchKernelGGL(attn_flash2w, dim3(98*8, 2, 2), dim3(128), 0, stream,
                       qkt_hi, qkt_lo, vbf, xhi, xlo, mlbase);
    hipLaunchKernelGGL(combine, dim3(392, 2), dim3(256), 0, stream,
                       xhi, xlo, mlbase, x, gm, out);
}

// Round 6
// 324.232 us; speedup vs baseline: 1.3260x; 1.0262x over previous
//
#include <hip/hip_runtime.h>
#include <math.h>

// Problem constants
#define B_ 8
#define C_ 256
#define H_ 56
#define W_ 56
#define N_ 3136  // 56*56 = 49*64
#define BN_ (B_*N_)
#define LOG2E 1.44269504088896340736f

typedef __attribute__((ext_vector_type(8))) short short8;
typedef __attribute__((ext_vector_type(4))) float f32x4;
typedef __attribute__((ext_vector_type(16))) float f32x16;
typedef __attribute__((ext_vector_type(4))) unsigned short u16x4;
#define MFMA16(A, Bf, Cf) __builtin_amdgcn_mfma_f32_16x16x32_bf16((A), (Bf), (Cf), 0, 0, 0)
#define MFMA32(A, Bf, Cf) __builtin_amdgcn_mfma_f32_32x32x16_bf16((A), (Bf), (Cf), 0, 0, 0)

// -------------------- workspace layout (ushort units) --------------------
#define XT_ELEMS (B_*58*64*256)           // 7,602,176
#define A_ELEMS  (320*2304)               // 737,280
#define AHI_OFF  (2*XT_ELEMS)
#define ALO_OFF  (AHI_OFF + A_ELEMS)
#define QKT_HI_OFF (ALO_OFF + A_ELEMS)
#define QKT_ELEMS  (B_*N_*64)             // 1,605,632 = QF_ELEMS + KF_ELEMS
#define QKT_LO_OFF (QKT_HI_OFF + QKT_ELEMS)
#define VBF_OFF    (QKT_LO_OFF + QKT_ELEMS)
#define VBF_ELEMS  (B_*C_*N_)             // 6,422,528

// Fragment-order layouts: attn lane L reads base + L*16B.
// Qf: [b][q16 (pix>>4, 196)][fq*16 + ln (64)][8]   (features 0..31, PRE-SCALED by log2e)
// Kf: [b][jt (49)][tj (4)][fq*16 + ln (64)][8]     (features 32..63)
// Vf: [b][cg (8)][jt (49)][s (4)][hh*32 + c31 (64)][8]
#define QF_ELEMS (B_*196*64*8)            // 802,816

// Af fragment-order weights: [rowgrp 20][s 9][cc 8][L 64][8]

// LDS swizzle for conv B-slabs: chunk (r,col,c8) -> uint4 index
#define SWZ(r, col, c8) ((((r)*64 + (col))*4) + ((c8) ^ ((col) & 3)))

// P LDS row stride (ushorts) for attn
#define PSTR 76
// Vs (conv v-epilogue LDS transpose) pixel stride
#define VSTR 58

__device__ inline unsigned short f2bf(float f) {
    unsigned u = __float_as_uint(f);
    unsigned r = (u + 0x7fffu + ((u >> 16) & 1u)) >> 16;   // RNE
    return (unsigned short)r;
}
__device__ inline float bf2f(unsigned short h) {
    return __uint_as_float(((unsigned)h) << 16);
}
// HW 2^x (v_exp_f32 computes exp2 natively)
__device__ inline float exp2_hw(float x) {
    float r; asm("v_exp_f32 %0, %1" : "=v"(r) : "v"(x)); return r;
}
// pack 2 f32 -> 2 bf16 in one u32 (RNE, bit-identical to f2bf)
__device__ inline unsigned cvt_pk_bf16(float lo, float hi) {
    unsigned r; asm("v_cvt_pk_bf16_f32 %0, %1, %2" : "=v"(r) : "v"(lo), "v"(hi)); return r;
}

// ---------------------------------------------------------------------------
// Kernel 0: zero ONLY the pad rows/cols (R6: was zeroing 30MB; pads = 2MB.
// Cols 58..63 stay garbage: they feed only discarded MFMA output columns,
// and MFMA output elements are independent dot products).
// ---------------------------------------------------------------------------
__global__ __launch_bounds__(256) void zero_pads(
    unsigned short* __restrict__ xhi, unsigned short* __restrict__ xlo)
{
    const int g = blockIdx.x*256 + threadIdx.x;   // uint4 units, 2*61440 total
    const int half = 61440;
    unsigned short* base = (g < half) ? xhi : xlo;
    const int i = (g < half) ? g : g - half;
    const int b = i / 7680, rem = i - b*7680;
    const int slot = rem >> 5, c8 = rem & 31;
    int row, col;
    if (slot < 64)       { row = 0;  col = slot; }
    else if (slot < 128) { row = 57; col = slot - 64; }
    else if (slot < 184) { row = slot - 127; col = 0; }   // rows 1..56
    else                 { row = slot - 183; col = 57; }  // rows 1..56
    const size_t o = ((size_t)((b*58 + row)*64 + col))*256 + c8*8;
    *(uint4*)(base + o) = make_uint4(0, 0, 0, 0);
}

// ---------------------------------------------------------------------------
// Kernel 1a: x (fp32 NCHW) -> padded pixel-major bf16 hi/lo.
// ---------------------------------------------------------------------------
__global__ __launch_bounds__(256) void prep_x(
    const float* __restrict__ x,
    unsigned short* __restrict__ xhi, unsigned short* __restrict__ xlo)
{
    __shared__ float xs[64][57];
    const int cc = blockIdx.x, y = blockIdx.y, b = blockIdx.z;
    const int t = threadIdx.x;
    const int c0 = cc * 64;
    for (int idx = t; idx < 64 * 56; idx += 256) {
        const int ch = idx / 56, xc = idx - ch * 56;
        xs[ch][xc] = x[((size_t)(b*C_ + c0 + ch)*H_ + y)*W_ + xc];
    }
    __syncthreads();
    for (int idx = t; idx < 56 * 32; idx += 256) {
        const int xc = idx >> 5, chp = idx & 31;
        const float v0 = xs[2*chp][xc], v1 = xs[2*chp + 1][xc];
        const unsigned short h0 = f2bf(v0), h1 = f2bf(v1);
        const unsigned short l0 = f2bf(v0 - bf2f(h0));
        const unsigned short l1 = f2bf(v1 - bf2f(h1));
        const size_t o = ((size_t)(b*58 + y + 1) * 64 + (xc + 1)) * 256 + c0 + 2*chp;
        *(unsigned*)(xhi + o) = (unsigned)h0 | ((unsigned)h1 << 16);
        *(unsigned*)(xlo + o) = (unsigned)l0 | ((unsigned)l1 << 16);
    }
}

// ---------------------------------------------------------------------------
// Kernel 1b: weights -> Af_hi/Af_lo FRAGMENT order.
// ---------------------------------------------------------------------------
__global__ __launch_bounds__(256) void prep_w(
    const float* __restrict__ wq, const float* __restrict__ wk,
    const float* __restrict__ wv,
    unsigned short* __restrict__ Ahi, unsigned short* __restrict__ Alo)
{
    const int g = blockIdx.x * 256 + threadIdx.x;
    if (g >= 320 * 2304) return;
    const int m = g / 2304, k = g - m * 2304;
    const int s = k >> 8, c = k & 255;
    float w;
    if (m < 32)      w = wq[((size_t)m*C_ + c)*9 + s];
    else if (m < 64) w = wk[((size_t)(m-32)*C_ + c)*9 + s];
    else             w = wv[((size_t)(m-64)*C_ + c)*9 + s];
    const unsigned short h = f2bf(w);
    const int cc = (k >> 5) & 7, quad = (k >> 3) & 3, e = k & 7;
    const size_t o = ((((size_t)(m >> 4)*9 + s)*8 + cc)*64 + (quad*16 + (m & 15)))*8 + e;
    Ahi[o] = h;
    Alo[o] = f2bf(w - bf2f(h));
}

// ---------------------------------------------------------------------------
// Kernel 2: FUSED conv. grid (b 8, y 56, z 3), block 256 = 4 waves.
//   z == 0      -> q/k conv (hi/lo 3-MFMA); Q scaled by log2e (R6: exp2 softmax)
//   z in 1..2   -> v conv, 128 channels, 2 row-groups/wave
// ---------------------------------------------------------------------------
__global__ __launch_bounds__(256) void conv_fused(
    const unsigned short* __restrict__ xhi, const unsigned short* __restrict__ xlo,
    const unsigned short* __restrict__ Ahi, const unsigned short* __restrict__ Alo,
    const float* __restrict__ bq, const float* __restrict__ bk,
    const float* __restrict__ bv,
    unsigned short* __restrict__ qkt_hi, unsigned short* __restrict__ qkt_lo,
    unsigned short* __restrict__ vbf)
{
    __shared__ uint4 SMEM[1552];       // 24.8 KB: sH | sL (qk) ; Vs overlay (v)
    uint4* sH = SMEM;
    uint4* sL = SMEM + 776;
    const int b = blockIdx.x, y = blockIdx.y, z = blockIdx.z;
    const int t = threadIdx.x;
    const int w = t >> 6, L = t & 63;
    const int ln = L & 15, quad = L >> 4;

    if (z == 0) {
        // ---------------- q/k path (hi/lo 3-MFMA) ----------------
        f32x4 acc[4];
#pragma unroll
        for (int nt = 0; nt < 4; nt++) acc[nt] = (f32x4)0.0f;

        uint4 ph[3], pl[3];
#pragma unroll
        for (int i = 0; i < 3; i++) {
            const int idx = t + i*256;
            const int r = idx >> 8, col = (idx >> 2) & 63, c8 = idx & 3;
            const size_t go = ((size_t)((b*58 + y + r)*64 + col))*256 + c8*8;
            ph[i] = *(const uint4*)(xhi + go);
            pl[i] = *(const uint4*)(xlo + go);
        }

        for (int cc = 0; cc < 8; cc++) {
            __syncthreads();
#pragma unroll
            for (int i = 0; i < 3; i++) {
                const int idx = t + i*256;
                const int r = idx >> 8, col = (idx >> 2) & 63, c8 = idx & 3;
                sH[SWZ(r, col, c8)] = ph[i];
                sL[SWZ(r, col, c8)] = pl[i];
            }
            __syncthreads();
            if (cc < 7) {
#pragma unroll
                for (int i = 0; i < 3; i++) {
                    const int idx = t + i*256;
                    const int r = idx >> 8, col = (idx >> 2) & 63, c8 = idx & 3;
                    const size_t go = ((size_t)((b*58 + y + r)*64 + col))*256 + (cc+1)*32 + c8*8;
                    ph[i] = *(const uint4*)(xhi + go);
                    pl[i] = *(const uint4*)(xlo + go);
                }
            }
#pragma unroll
            for (int s = 0; s < 9; s++) {
                const int dx = s % 3 - 1;
                const int r = s / 3;
                const size_t aoff = (((size_t)(w*9 + s)*8 + cc)*64 + L)*8;
                const short8 ah = *(const short8*)(Ahi + aoff);
                const short8 al = *(const short8*)(Alo + aoff);
#pragma unroll
                for (int nt = 0; nt < 4; nt++) {
                    const int col = nt*16 + ln + dx + 1;
                    const int i4 = SWZ(r, col, quad);
                    const short8 bh = *(const short8*)&sH[i4];
                    const short8 bl = *(const short8*)&sL[i4];
                    acc[nt] = MFMA16(ah, bh, acc[nt]);
                    acc[nt] = MFMA16(ah, bl, acc[nt]);
                    acc[nt] = MFMA16(al, bh, acc[nt]);
                }
            }
        }

        // epilogue: fragment-order Qf/Kf writes; Q pre-scaled by log2e
#pragma unroll
        for (int nt = 0; nt < 4; nt++) {
            const int px = nt*16 + ln;
            if (px >= 56) continue;
            const int pix = y*56 + px;
            u16x4 hi4, lo4;
#pragma unroll
            for (int r = 0; r < 4; r++) {
                const int m = w*16 + quad*4 + r;
                const float bias = (m < 32) ? bq[m] : bk[m - 32];
                float val = acc[nt][r] + bias;
                if (w < 2) val *= LOG2E;       // Q only: exp2-domain softmax
                const unsigned short h = f2bf(val);
                hi4[r] = h;
                lo4[r] = f2bf(val - bf2f(h));
            }
            const int m0 = w*16 + quad*4;
            size_t o;
            if (w < 2) {
                o = ((size_t)(b*196 + (pix >> 4))*64 + (m0 >> 3)*16 + (pix & 15))*8 + (m0 & 7);
            } else {
                const int mk0 = m0 - 32;
                o = (size_t)QF_ELEMS +
                    (((size_t)(b*49 + (pix >> 6))*4 + ((pix >> 4) & 3))*64
                     + (mk0 >> 3)*16 + (pix & 15))*8 + (mk0 & 7);
            }
            *(u16x4*)(qkt_hi + o) = hi4;
            *(u16x4*)(qkt_lo + o) = lo4;
        }
    } else {
        // ------- v path: 128 channels, 2 row-groups per wave -------
        const int mg = z - 1;              // 0 or 1

        f32x4 acc[2][4];
#pragma unroll
        for (int g2 = 0; g2 < 2; g2++)
#pragma unroll
            for (int nt = 0; nt < 4; nt++) acc[g2][nt] = (f32x4)0.0f;

        uint4 ph[3];
#pragma unroll
        for (int i = 0; i < 3; i++) {
            const int idx = t + i*256;
            const int r = idx >> 8, col = (idx >> 2) & 63, c8 = idx & 3;
            const size_t go = ((size_t)((b*58 + y + r)*64 + col))*256 + c8*8;
            ph[i] = *(const uint4*)(xhi + go);
        }

        for (int cc = 0; cc < 8; cc++) {
            __syncthreads();
#pragma unroll
            for (int i = 0; i < 3; i++) {
                const int idx = t + i*256;
                const int r = idx >> 8, col = (idx >> 2) & 63, c8 = idx & 3;
                sH[SWZ(r, col, c8)] = ph[i];
            }
            __syncthreads();
            if (cc < 7) {
#pragma unroll
                for (int i = 0; i < 3; i++) {
                    const int idx = t + i*256;
                    const int r = idx >> 8, col = (idx >> 2) & 63, c8 = idx & 3;
                    const size_t go = ((size_t)((b*58 + y + r)*64 + col))*256 + (cc+1)*32 + c8*8;
                    ph[i] = *(const uint4*)(xhi + go);
                }
            }
#pragma unroll
            for (int s = 0; s < 9; s++) {
                const int dx = s % 3 - 1;
                const int r = s / 3;
                const size_t a0off = (((size_t)((4 + mg*8 + w*2)*9 + s)*8 + cc)*64 + L)*8;
                const short8 a0 = *(const short8*)(Ahi + a0off);
                const short8 a1 = *(const short8*)(Ahi + a0off + 9*8*64*8);
#pragma unroll
                for (int nt = 0; nt < 4; nt++) {
                    const int col = nt*16 + ln + dx + 1;
                    const short8 bf = *(const short8*)&sH[SWZ(r, col, quad)];
                    acc[0][nt] = MFMA16(a0, bf, acc[0][nt]);
                    acc[1][nt] = MFMA16(a1, bf, acc[1][nt]);
                }
            }
        }

        // ---- epilogue: LDS transpose (128ch x 56px) -> dense Vf tiles ----
        __syncthreads();
        unsigned short* Vs = (unsigned short*)SMEM;   // [128][VSTR]
#pragma unroll
        for (int g2 = 0; g2 < 2; g2++)
#pragma unroll
            for (int nt = 0; nt < 4; nt++) {
                const int px = nt*16 + ln;
                if (px >= 56) continue;
#pragma unroll
                for (int r = 0; r < 4; r++) {
                    const int cl = (w*2 + g2)*16 + quad*4 + r;
                    Vs[cl*VSTR + px] = f2bf(acc[g2][nt][r] + bv[mg*128 + cl]);
                }
            }
        __syncthreads();
        const int p0 = y*56;
        const int hh = L >> 5;
        const int cg = mg*4 + w;
        const int gend = (p0 + 55) >> 4;
        for (int gi = p0 >> 4; gi <= gend; gi++) {
            const int pxl0 = gi*16 + hh*8 - p0;
            if (pxl0 >= 0 && pxl0 + 8 <= 56) {
                const short8 vv = *(const short8*)&Vs[(w*32 + (L & 31))*VSTR + pxl0];
                const size_t o = ((((size_t)(b*8 + cg)*49 + (gi >> 2))*4 + (gi & 3))*64 + L)*8;
                *(short8*)(vbf + o) = vv;
            }
        }
    }
}

// ---------------------------------------------------------------------------
// Kernel 3: fused flash attention (R6: exp2-domain, cvt_pk P-pack, defer-max).
// grid (98*8, chalf 2, jh 2), block 128 = 2 waves.
// ---------------------------------------------------------------------------
__global__ __launch_bounds__(128, 4) void attn_flash2w(
    const unsigned short* __restrict__ qkt_hi, const unsigned short* __restrict__ qkt_lo,
    const unsigned short* __restrict__ vbf,
    unsigned short* __restrict__ op0, unsigned short* __restrict__ op1,
    float* __restrict__ mlbase)
{
    __shared__ unsigned short P[2][32*PSTR];   // 9.5 KB
    __shared__ float alphaL[2][32];

    const int bx = blockIdx.x;
    const int b = bx & 7, it = bx >> 3;
    const int chalf = blockIdx.y;
    const int jh = blockIdx.z;
    const int jt0 = jh * 25, njt = 25 - jh;    // 25 / 24 tiles
    const int i_base = it * 32;
    const int t = threadIdx.x;
    const int w = t >> 6, L = t & 63;
    const int ln = L & 15, quad = L >> 4;
    const int l32 = L & 31, h32 = L >> 5;

    const unsigned short* Kf_hi = qkt_hi + QF_ELEMS;
    const unsigned short* Kf_lo = qkt_lo + QF_ELEMS;

    const size_t qoff = ((size_t)(b*196 + it*2 + w)*64 + L)*8;
    const short8 qh = *(const short8*)(qkt_hi + qoff);
    const short8 ql = *(const short8*)(qkt_lo + qoff);

    float m_run = -INFINITY, l_run = 0.0f;
    f32x16 O0 = (f32x16)0.0f, O1 = (f32x16)0.0f;
    const int cg0 = chalf*4 + w*2;
    const unsigned short* vt0 = vbf + ((size_t)(b*8 + cg0)*49)*2048 + (size_t)L*8;
    const unsigned short* vt1 = vbf + ((size_t)(b*8 + cg0 + 1)*49)*2048 + (size_t)L*8;
    const unsigned short* kbh = Kf_hi + (size_t)b*49*2048 + (size_t)L*8;
    const unsigned short* kbl = Kf_lo + (size_t)b*49*2048 + (size_t)L*8;

    for (int jtl = 0; jtl < njt; jtl++) {
        const int jt = jt0 + jtl;
        const int buf = jtl & 1;

        short8 Va[4], Vb[4];
#pragma unroll
        for (int s = 0; s < 4; s++) {
            Va[s] = *(const short8*)(vt0 + jt*2048 + s*512);
            Vb[s] = *(const short8*)(vt1 + jt*2048 + s*512);
        }

        f32x4 sacc[4];
#pragma unroll
        for (int tj = 0; tj < 4; tj++) {
            const short8 kh = *(const short8*)(kbh + jt*2048 + tj*512);
            const short8 kl = *(const short8*)(kbl + jt*2048 + tj*512);
            f32x4 a = (f32x4)0.0f;
            a = MFMA16(kh, qh, a);
            a = MFMA16(kh, ql, a);
            a = MFMA16(kl, qh, a);
            sacc[tj] = a;
        }
        float mt0 = fmaxf(fmaxf(sacc[0][0], sacc[0][1]), fmaxf(sacc[0][2], sacc[0][3]));
        float mt1 = fmaxf(fmaxf(sacc[1][0], sacc[1][1]), fmaxf(sacc[1][2], sacc[1][3]));
        float mt2 = fmaxf(fmaxf(sacc[2][0], sacc[2][1]), fmaxf(sacc[2][2], sacc[2][3]));
        float mt3 = fmaxf(fmaxf(sacc[3][0], sacc[3][1]), fmaxf(sacc[3][2], sacc[3][3]));
        float mx = fmaxf(fmaxf(mt0, mt1), fmaxf(mt2, mt3));
        mx = fmaxf(mx, __shfl_xor(mx, 16));
        mx = fmaxf(mx, __shfl_xor(mx, 32));

        // defer-max (T13): only raise m when growth exceeds 8 (P <= 2^8, bf16-safe)
        float alpha = 1.0f;
        if (__any(mx > m_run + 8.0f)) {
            const float m_new = fmaxf(m_run, mx);
            alpha = exp2_hw(m_run - m_new);
            m_run = m_new;
        }

#pragma unroll
        for (int tj = 0; tj < 4; tj++)
#pragma unroll
            for (int r = 0; r < 4; r++)
                sacc[tj][r] = exp2_hw(sacc[tj][r] - m_run);
        float s0 = (sacc[0][0] + sacc[0][1]) + (sacc[0][2] + sacc[0][3]);
        float s1 = (sacc[1][0] + sacc[1][1]) + (sacc[1][2] + sacc[1][3]);
        float s2 = (sacc[2][0] + sacc[2][1]) + (sacc[2][2] + sacc[2][3]);
        float s3 = (sacc[3][0] + sacc[3][1]) + (sacc[3][2] + sacc[3][3]);
        float ps = (s0 + s1) + (s2 + s3);
        ps += __shfl_xor(ps, 16);
        ps += __shfl_xor(ps, 32);
        l_run = l_run * alpha + ps;

        {
            unsigned short* prow = &P[buf][(w*16 + ln)*PSTR];
#pragma unroll
            for (int tj = 0; tj < 4; tj++) {
                uint2 pp;
                pp.x = cvt_pk_bf16(sacc[tj][0], sacc[tj][1]);
                pp.y = cvt_pk_bf16(sacc[tj][2], sacc[tj][3]);
                *(uint2*)(prow + tj*16 + quad*4) = pp;
            }
        }
        if (quad == 0) alphaL[buf][w*16 + ln] = alpha;

        __syncthreads();

        const float a = alphaL[buf][l32];
        if (__any(a != 1.0f)) {
#pragma unroll
            for (int rg = 0; rg < 16; rg++) { O0[rg] *= a; O1[rg] *= a; }
        }
        short8 Bp[4];
#pragma unroll
        for (int s = 0; s < 4; s++) {
            Bp[s] = *(const short8*)&P[buf][l32*PSTR + s*16 + h32*8];
            O0 = MFMA32(Va[s], Bp[s], O0);
        }
#pragma unroll
        for (int s = 0; s < 4; s++)
            O1 = MFMA32(Vb[s], Bp[s], O1);
    }

    if (chalf == 0 && quad == 0) {
        const int i = i_base + w*16 + ln;
        mlbase[jh*BN_ + b*N_ + i]       = m_run;
        mlbase[(2 + jh)*BN_ + b*N_ + i] = l_run;
    }
    unsigned short* OP = jh ? op1 : op0;
    const int pix = i_base + l32;
#pragma unroll
    for (int g = 0; g < 2; g++) {
        const f32x16 Ot = g ? O1 : O0;
        const int cg = chalf*128 + w*64 + g*32;
#pragma unroll
        for (int reg = 0; reg < 16; reg++) {
            const int c = cg + (reg & 3) + 8*(reg >> 2) + 4*h32;
            OP[(size_t)(b*C_ + c)*N_ + pix] = f2bf(Ot[reg]);
        }
    }
}

// ---------------------------------------------------------------------------
// Kernel 3b: per-pixel combine coefficients (exp2 domain, gamma folded).
// ---------------------------------------------------------------------------
__global__ __launch_bounds__(256) void coef_pre(
    const float* __restrict__ mlbase, const float* __restrict__ gptr,
    float* __restrict__ coef)
{
    const int i = blockIdx.x*256 + threadIdx.x;   // 0..BN-1
    const float m0 = mlbase[i],        m1 = mlbase[BN_ + i];
    const float l0 = mlbase[2*BN_ + i], l1 = mlbase[3*BN_ + i];
    const float mm = fmaxf(m0, m1);
    const float a0 = exp2_hw(m0 - mm), a1 = exp2_hw(m1 - mm);
    const float inv = gptr[0] / (a0*l0 + a1*l1);
    coef[2*i]   = a0 * inv;
    coef[2*i+1] = a1 * inv;
}

// ---------------------------------------------------------------------------
// Kernel 4: combine, vectorized (R6): 4 px/thread, ushort4/float4.
// grid (2048) = b*256 + c, block 256.
// ---------------------------------------------------------------------------
__global__ __launch_bounds__(256) void combine(
    const unsigned short* __restrict__ op0, const unsigned short* __restrict__ op1,
    const float* __restrict__ coef,
    const float* __restrict__ x, float* __restrict__ out)
{
    const int bc = blockIdx.x;
    const int b = bc >> 8;
    const size_t base = (size_t)bc * N_;
    const float2* cf = (const float2*)coef + (size_t)b * N_;
    for (int pq = threadIdx.x; pq < 784; pq += 256) {
        const int p0 = pq * 4;
        const ushort4 o0 = *(const ushort4*)(op0 + base + p0);
        const ushort4 o1 = *(const ushort4*)(op1 + base + p0);
        const float4 xx = *(const float4*)(x + base + p0);
        float4 r;
        {
            const float2 c = cf[p0 + 0];
            r.x = xx.x + c.x*bf2f(o0.x) + c.y*bf2f(o1.x);
        }
        {
            const float2 c = cf[p0 + 1];
            r.y = xx.y + c.x*bf2f(o0.y) + c.y*bf2f(o1.y);
        }
        {
            const float2 c = cf[p0 + 2];
            r.z = xx.z + c.x*bf2f(o0.z) + c.y*bf2f(o1.z);
        }
        {
            const float2 c = cf[p0 + 3];
            r.w = xx.w + c.x*bf2f(o0.w) + c.y*bf2f(o1.w);
        }
        *(float4*)(out + base + p0) = r;
    }
}

// ---------------------------------------------------------------------------
extern "C" void kernel_launch(void* const* d_in, const int* in_sizes, int n_in,
                              void* d_out, int out_size, void* d_ws, size_t ws_size,
                              hipStream_t stream)
{
    (void)in_sizes; (void)n_in; (void)out_size; (void)ws_size;
    const float* x  = (const float*)d_in[0];
    const float* wq = (const float*)d_in[1];
    const float* bq = (const float*)d_in[2];
    const float* wk = (const float*)d_in[3];
    const float* bk = (const float*)d_in[4];
    const float* wv = (const float*)d_in[5];
    const float* bv = (const float*)d_in[6];
    const float* gm = (const float*)d_in[7];
    float* out = (float*)d_out;

    unsigned short* u = (unsigned short*)d_ws;
    unsigned short* xhi = u;                      // conv input; later O-partial jh=0
    unsigned short* xlo = u + XT_ELEMS;           // conv input; later O-partial jh=1
    unsigned short* Ahi = u + AHI_OFF;            // Af weights; first 400KB later m/l
    unsigned short* Alo = u + ALO_OFF;            // Af lo; later coef table (200KB)
    unsigned short* qkt_hi = u + QKT_HI_OFF;      // [Qf_hi | Kf_hi] fragment-order
    unsigned short* qkt_lo = u + QKT_LO_OFF;      // [Qf_lo | Kf_lo]
    unsigned short* vbf = u + VBF_OFF;            // Vf fragment-order
    float* mlbase = (float*)Ahi;                  // 4 * B*N floats = 401 KB
    float* coef = (float*)Alo;                    // 2 * B*N floats = 200 KB

    hipLaunchKernelGGL(zero_pads, dim3(480), dim3(256), 0, stream, xhi, xlo);
    hipLaunchKernelGGL(prep_x, dim3(4, 56, 8), dim3(256), 0, stream, x, xhi, xlo);
    hipLaunchKernelGGL(prep_w, dim3(2880), dim3(256), 0, stream, wq, wk, wv, Ahi, Alo);
    hipLaunchKernelGGL(conv_fused, dim3(8, 56, 3), dim3(256), 0, stream,
                       xhi, xlo, Ahi, Alo, bq, bk, bv, qkt_hi, qkt_lo, vbf);
    hipLaunchKernelGGL(attn_flash2w, dim3(98*8, 2, 2), dim3(128), 0, stream,
                       qkt_hi, qkt_lo, vbf, xhi, xlo, mlbase);
    hipLaunchKernelGGL(coef_pre, dim3(98), dim3(256), 0, stream, mlbase, gm, coef);
    hipLaunchKernelGGL(combine, dim3(2048), dim3(256), 0, stream,
                       xhi, xlo, coef, x, out);
}

// Round 7
// 307.028 us; speedup vs baseline: 1.4003x; 1.0560x over previous
//
#include <hip/hip_runtime.h>
#include <math.h>

// Problem constants
#define B_ 8
#define C_ 256
#define H_ 56
#define W_ 56
#define N_ 3136  // 56*56 = 49*64
#define BN_ (B_*N_)
#define LOG2E 1.44269504088896340736f

typedef __attribute__((ext_vector_type(8))) short short8;
typedef __attribute__((ext_vector_type(4))) float f32x4;
typedef __attribute__((ext_vector_type(16))) float f32x16;
typedef __attribute__((ext_vector_type(4))) unsigned short u16x4;
#define MFMA16(A, Bf, Cf) __builtin_amdgcn_mfma_f32_16x16x32_bf16((A), (Bf), (Cf), 0, 0, 0)
#define MFMA32(A, Bf, Cf) __builtin_amdgcn_mfma_f32_32x32x16_bf16((A), (Bf), (Cf), 0, 0, 0)

// -------------------- workspace layout (ushort units) --------------------
#define XT_ELEMS (B_*58*64*256)           // 7,602,176
#define A_ELEMS  (320*2304)               // 737,280
#define AHI_OFF  (2*XT_ELEMS)
#define ALO_OFF  (AHI_OFF + A_ELEMS)
#define QKT_HI_OFF (ALO_OFF + A_ELEMS)
#define QKT_ELEMS  (B_*N_*64)             // 1,605,632 = QF_ELEMS + KF_ELEMS
#define QKT_LO_OFF (QKT_HI_OFF + QKT_ELEMS)
#define VBF_OFF    (QKT_LO_OFF + QKT_ELEMS)
#define VBF_ELEMS  (B_*C_*N_)             // 6,422,528

// Fragment-order layouts: attn lane L reads base + L*16B.
// Qf: [b][q16 (pix>>4, 196)][fq*16 + ln (64)][8]   (features 0..31, PRE-SCALED by log2e)
// Kf: [b][jt (49)][tj (4)][fq*16 + ln (64)][8]     (features 32..63)
// Vf: [b][cg (8)][jt (49)][s (4)][hh*32 + c31 (64)][8]
#define QF_ELEMS (B_*196*64*8)            // 802,816

// Af fragment-order weights: [rowgrp 20][s 9][cc 8][L 64][8]

// LDS swizzle for conv B-slabs (R7: extra (col>>2) term -> 2-way instead of
// 4-way ds_read bank aliasing; 2-way is free per m136).
#define SX(col) ((((col) & 3)) ^ (((col) >> 2) & 3))
#define SWZ(r, col, c8) ((((r)*64 + (col))*4) + ((c8) ^ SX(col)))

// P LDS row stride (ushorts) for attn
#define PSTR 76
// Vs (conv v-epilogue LDS transpose) pixel stride
#define VSTR 58

__device__ inline unsigned short f2bf(float f) {
    unsigned u = __float_as_uint(f);
    unsigned r = (u + 0x7fffu + ((u >> 16) & 1u)) >> 16;   // RNE
    return (unsigned short)r;
}
__device__ inline float bf2f(unsigned short h) {
    return __uint_as_float(((unsigned)h) << 16);
}
__device__ inline float exp2_hw(float x) {
    float r; asm("v_exp_f32 %0, %1" : "=v"(r) : "v"(x)); return r;
}
__device__ inline unsigned cvt_pk_bf16(float lo, float hi) {
    unsigned r; asm("v_cvt_pk_bf16_f32 %0, %1, %2" : "=v"(r) : "v"(lo), "v"(hi)); return r;
}
// direct global->LDS DMA, 16B/lane; LDS dest = (wave-uniform base) + lane*16
__device__ inline void gl_lds16(const unsigned short* g, uint4* l) {
    __builtin_amdgcn_global_load_lds(
        (const __attribute__((address_space(1))) unsigned int*)g,
        (__attribute__((address_space(3))) unsigned int*)l,
        16, 0, 0);
}

// ---------------------------------------------------------------------------
// Kernel 0: zero ONLY the pad rows/cols.
// ---------------------------------------------------------------------------
__global__ __launch_bounds__(256) void zero_pads(
    unsigned short* __restrict__ xhi, unsigned short* __restrict__ xlo)
{
    const int g = blockIdx.x*256 + threadIdx.x;   // uint4 units, 2*61440 total
    const int half = 61440;
    unsigned short* base = (g < half) ? xhi : xlo;
    const int i = (g < half) ? g : g - half;
    const int b = i / 7680, rem = i - b*7680;
    const int slot = rem >> 5, c8 = rem & 31;
    int row, col;
    if (slot < 64)       { row = 0;  col = slot; }
    else if (slot < 128) { row = 57; col = slot - 64; }
    else if (slot < 184) { row = slot - 127; col = 0; }   // rows 1..56
    else                 { row = slot - 183; col = 57; }  // rows 1..56
    const size_t o = ((size_t)((b*58 + row)*64 + col))*256 + c8*8;
    *(uint4*)(base + o) = make_uint4(0, 0, 0, 0);
}

// ---------------------------------------------------------------------------
// Kernel 1a: x (fp32 NCHW) -> padded pixel-major bf16 hi/lo.
// ---------------------------------------------------------------------------
__global__ __launch_bounds__(256) void prep_x(
    const float* __restrict__ x,
    unsigned short* __restrict__ xhi, unsigned short* __restrict__ xlo)
{
    __shared__ float xs[64][57];
    const int cc = blockIdx.x, y = blockIdx.y, b = blockIdx.z;
    const int t = threadIdx.x;
    const int c0 = cc * 64;
    for (int idx = t; idx < 64 * 56; idx += 256) {
        const int ch = idx / 56, xc = idx - ch * 56;
        xs[ch][xc] = x[((size_t)(b*C_ + c0 + ch)*H_ + y)*W_ + xc];
    }
    __syncthreads();
    for (int idx = t; idx < 56 * 32; idx += 256) {
        const int xc = idx >> 5, chp = idx & 31;
        const float v0 = xs[2*chp][xc], v1 = xs[2*chp + 1][xc];
        const unsigned short h0 = f2bf(v0), h1 = f2bf(v1);
        const unsigned short l0 = f2bf(v0 - bf2f(h0));
        const unsigned short l1 = f2bf(v1 - bf2f(h1));
        const size_t o = ((size_t)(b*58 + y + 1) * 64 + (xc + 1)) * 256 + c0 + 2*chp;
        *(unsigned*)(xhi + o) = (unsigned)h0 | ((unsigned)h1 << 16);
        *(unsigned*)(xlo + o) = (unsigned)l0 | ((unsigned)l1 << 16);
    }
}

// ---------------------------------------------------------------------------
// Kernel 1b: weights -> Af_hi/Af_lo FRAGMENT order.
// ---------------------------------------------------------------------------
__global__ __launch_bounds__(256) void prep_w(
    const float* __restrict__ wq, const float* __restrict__ wk,
    const float* __restrict__ wv,
    unsigned short* __restrict__ Ahi, unsigned short* __restrict__ Alo)
{
    const int g = blockIdx.x * 256 + threadIdx.x;
    if (g >= 320 * 2304) return;
    const int m = g / 2304, k = g - m * 2304;
    const int s = k >> 8, c = k & 255;
    float w;
    if (m < 32)      w = wq[((size_t)m*C_ + c)*9 + s];
    else if (m < 64) w = wk[((size_t)(m-32)*C_ + c)*9 + s];
    else             w = wv[((size_t)(m-64)*C_ + c)*9 + s];
    const unsigned short h = f2bf(w);
    const int cc = (k >> 5) & 7, quad = (k >> 3) & 3, e = k & 7;
    const size_t o = ((((size_t)(m >> 4)*9 + s)*8 + cc)*64 + (quad*16 + (m & 15)))*8 + e;
    Ahi[o] = h;
    Alo[o] = f2bf(w - bf2f(h));
}

// ---------------------------------------------------------------------------
// Kernel 2: FUSED conv, R7. grid (b 8, y 56, z 2), block 256 = 4 waves.
//   z == 0 -> q/k (hi/lo 3-MFMA), 2x2 wave-tiling: wave = 2 rowgrp x 2 pxtile
//             -> 6 MFMA per 2KB B-read (was 3).
//   z == 1 -> v, ALL 256 ch: wave = 4 rowgrp x 4 pxtile -> 4 MFMA per 1KB.
// Staging: global_load_lds direct L2->LDS (no VGPR round-trip, no ds_write),
// double-buffered, ONE barrier per cc. Swizzle preserved by inverse-swizzling
// the per-lane GLOBAL address (LDS dest stays wave-linear).
// ---------------------------------------------------------------------------
__global__ __launch_bounds__(256, 3) void conv_fused(
    const unsigned short* __restrict__ xhi, const unsigned short* __restrict__ xlo,
    const unsigned short* __restrict__ Ahi, const unsigned short* __restrict__ Alo,
    const float* __restrict__ bq, const float* __restrict__ bk,
    const float* __restrict__ bv,
    unsigned short* __restrict__ qkt_hi, unsigned short* __restrict__ qkt_lo,
    unsigned short* __restrict__ vbf)
{
    // [buf0 hi 768 | buf0 lo 768 | buf1 hi 768 | buf1 lo 768 | 8 overrun pad]
    // v path uses [buf0 768 | buf1 768]; epilogue transpose overlays 1856.
    __shared__ uint4 SMEM[3080];   // 49.3 KB -> 3 blocks/CU
    const int b = blockIdx.x, y = blockIdx.y, z = blockIdx.z;
    const int t = threadIdx.x;
    const int w = t >> 6, L = t & 63;
    const int ln = L & 15, quad = L >> 4;

    // staging: chunk ci = w*192 + i*64 + L -> (r,col,c8) with inverse swizzle
    size_t gofs[3];
#pragma unroll
    for (int i = 0; i < 3; i++) {
        const int ci = w*192 + i*64 + L;
        const int r = ci >> 8, col = (ci >> 2) & 63;
        const int c8 = (ci & 3) ^ SX(col);
        gofs[i] = ((size_t)((b*58 + y + r)*64 + col))*256 + c8*8;
    }

    if (z == 0) {
        // ---------------- q/k path: 2 rowgrp x 2 pxtile per wave ----------
        const int wrg = w >> 1, wnt = w & 1;
        f32x4 acc[2][2];
#pragma unroll
        for (int i = 0; i < 2; i++) { acc[i][0] = (f32x4)0.0f; acc[i][1] = (f32x4)0.0f; }

        // prologue: stage cc=0 into buf0
#pragma unroll
        for (int i = 0; i < 3; i++) {
            gl_lds16(xhi + gofs[i], SMEM + w*192 + i*64);
            gl_lds16(xlo + gofs[i], SMEM + 768 + w*192 + i*64);
        }
        __syncthreads();

        for (int cc = 0; cc < 8; cc++) {
            const int buf = cc & 1;
            const uint4* sH = SMEM + buf*1536;
            const uint4* sL = sH + 768;
            if (cc < 7) {   // fire-and-forget next-chunk DMA into other buf
                uint4* nB = SMEM + (buf^1)*1536;
#pragma unroll
                for (int i = 0; i < 3; i++) {
                    gl_lds16(xhi + gofs[i] + (cc+1)*32, nB + w*192 + i*64);
                    gl_lds16(xlo + gofs[i] + (cc+1)*32, nB + 768 + w*192 + i*64);
                }
            }
#pragma unroll
            for (int s = 0; s < 9; s++) {
                const int dx = s % 3 - 1;
                const int r = s / 3;
                short8 ah[2], al[2];
#pragma unroll
                for (int rgi = 0; rgi < 2; rgi++) {
                    const int rg = wrg*2 + rgi;
                    const size_t aoff = (((size_t)(rg*9 + s)*8 + cc)*64 + L)*8;
                    ah[rgi] = *(const short8*)(Ahi + aoff);
                    al[rgi] = *(const short8*)(Alo + aoff);
                }
#pragma unroll
                for (int nti = 0; nti < 2; nti++) {
                    const int col = (wnt*2 + nti)*16 + ln + dx + 1;
                    const int i4 = SWZ(r, col, quad);
                    const short8 bh = *(const short8*)&sH[i4];
                    const short8 bl = *(const short8*)&sL[i4];
#pragma unroll
                    for (int rgi = 0; rgi < 2; rgi++) {
                        acc[rgi][nti] = MFMA16(ah[rgi], bh, acc[rgi][nti]);
                        acc[rgi][nti] = MFMA16(ah[rgi], bl, acc[rgi][nti]);
                        acc[rgi][nti] = MFMA16(al[rgi], bh, acc[rgi][nti]);
                    }
                }
            }
            if (cc < 7) __syncthreads();   // staging(cc+1) drained + waves joined
        }

        // epilogue: fragment-order Qf/Kf writes; Q pre-scaled by log2e
#pragma unroll
        for (int rgi = 0; rgi < 2; rgi++) {
            const int rg = wrg*2 + rgi;
            const int m0 = rg*16 + quad*4;
#pragma unroll
            for (int nti = 0; nti < 2; nti++) {
                const int px = (wnt*2 + nti)*16 + ln;
                if (px >= 56) continue;
                const int pix = y*56 + px;
                u16x4 hi4, lo4;
#pragma unroll
                for (int r = 0; r < 4; r++) {
                    const int m = m0 + r;
                    const float bias = (m < 32) ? bq[m] : bk[m - 32];
                    float val = acc[rgi][nti][r] + bias;
                    if (rg < 2) val *= LOG2E;   // Q rows: exp2-domain softmax
                    const unsigned short h = f2bf(val);
                    hi4[r] = h;
                    lo4[r] = f2bf(val - bf2f(h));
                }
                size_t o;
                if (rg < 2) {
                    o = ((size_t)(b*196 + (pix >> 4))*64 + (m0 >> 3)*16 + (pix & 15))*8 + (m0 & 7);
                } else {
                    const int mk0 = m0 - 32;
                    o = (size_t)QF_ELEMS +
                        (((size_t)(b*49 + (pix >> 6))*4 + ((pix >> 4) & 3))*64
                         + (mk0 >> 3)*16 + (pix & 15))*8 + (mk0 & 7);
                }
                *(u16x4*)(qkt_hi + o) = hi4;
                *(u16x4*)(qkt_lo + o) = lo4;
            }
        }
    } else {
        // ------- v path: all 256 channels, 4 rowgroups per wave -------
        f32x4 acc[4][4];
#pragma unroll
        for (int rg = 0; rg < 4; rg++)
#pragma unroll
            for (int nt = 0; nt < 4; nt++) acc[rg][nt] = (f32x4)0.0f;

        // prologue: stage cc=0 (hi only) into buf0
#pragma unroll
        for (int i = 0; i < 3; i++)
            gl_lds16(xhi + gofs[i], SMEM + w*192 + i*64);
        __syncthreads();

        for (int cc = 0; cc < 8; cc++) {
            const int buf = cc & 1;
            const uint4* sH = SMEM + buf*768;
            if (cc < 7) {
                uint4* nB = SMEM + (buf^1)*768;
#pragma unroll
                for (int i = 0; i < 3; i++)
                    gl_lds16(xhi + gofs[i] + (cc+1)*32, nB + w*192 + i*64);
            }
#pragma unroll
            for (int s = 0; s < 9; s++) {
                const int dx = s % 3 - 1;
                const int r = s / 3;
                short8 a[4];
#pragma unroll
                for (int rg = 0; rg < 4; rg++) {
                    const size_t aoff = (((size_t)((4 + w*4 + rg)*9 + s)*8 + cc)*64 + L)*8;
                    a[rg] = *(const short8*)(Ahi + aoff);
                }
#pragma unroll
                for (int nt = 0; nt < 4; nt++) {
                    const int col = nt*16 + ln + dx + 1;
                    const short8 bf = *(const short8*)&sH[SWZ(r, col, quad)];
#pragma unroll
                    for (int rg = 0; rg < 4; rg++)
                        acc[rg][nt] = MFMA16(a[rg], bf, acc[rg][nt]);
                }
            }
            __syncthreads();   // staging(cc+1) drained; also guards epilogue overlay
        }

        // ---- epilogue: LDS transpose (256ch x 56px) -> dense Vf tiles ----
        unsigned short* Vs = (unsigned short*)SMEM;   // [256][VSTR] = 29.7 KB
#pragma unroll
        for (int rg = 0; rg < 4; rg++)
#pragma unroll
            for (int nt = 0; nt < 4; nt++) {
                const int px = nt*16 + ln;
                if (px >= 56) continue;
#pragma unroll
                for (int r = 0; r < 4; r++) {
                    const int cl = (w*4 + rg)*16 + quad*4 + r;   // 0..255
                    Vs[cl*VSTR + px] = f2bf(acc[rg][nt][r] + bv[cl]);
                }
            }
        __syncthreads();
        // readback: wave w stores channel-groups cg = 2w, 2w+1
        const int p0 = y*56;
        const int hh = L >> 5, c31 = L & 31;
        const int gend = (p0 + 55) >> 4;
        for (int gi = p0 >> 4; gi <= gend; gi++) {
            const int pxl0 = gi*16 + hh*8 - p0;
            if (pxl0 >= 0 && pxl0 + 8 <= 56) {
#pragma unroll
                for (int cgk = 0; cgk < 2; cgk++) {
                    const int cg = w*2 + cgk;
                    const short8 vv = *(const short8*)&Vs[(cg*32 + c31)*VSTR + pxl0];
                    const size_t o = ((((size_t)(b*8 + cg)*49 + (gi >> 2))*4 + (gi & 3))*64 + L)*8;
                    *(short8*)(vbf + o) = vv;
                }
            }
        }
    }
}

// ---------------------------------------------------------------------------
// Kernel 3: fused flash attention (exp2-domain, cvt_pk P-pack, defer-max).
// grid (98*8, chalf 2, jh 2), block 128 = 2 waves. Unchanged from R6.
// ---------------------------------------------------------------------------
__global__ __launch_bounds__(128, 4) void attn_flash2w(
    const unsigned short* __restrict__ qkt_hi, const unsigned short* __restrict__ qkt_lo,
    const unsigned short* __restrict__ vbf,
    unsigned short* __restrict__ op0, unsigned short* __restrict__ op1,
    float* __restrict__ mlbase)
{
    __shared__ unsigned short P[2][32*PSTR];   // 9.5 KB
    __shared__ float alphaL[2][32];

    const int bx = blockIdx.x;
    const int b = bx & 7, it = bx >> 3;
    const int chalf = blockIdx.y;
    const int jh = blockIdx.z;
    const int jt0 = jh * 25, njt = 25 - jh;    // 25 / 24 tiles
    const int i_base = it * 32;
    const int t = threadIdx.x;
    const int w = t >> 6, L = t & 63;
    const int ln = L & 15, quad = L >> 4;
    const int l32 = L & 31, h32 = L >> 5;

    const unsigned short* Kf_hi = qkt_hi + QF_ELEMS;
    const unsigned short* Kf_lo = qkt_lo + QF_ELEMS;

    const size_t qoff = ((size_t)(b*196 + it*2 + w)*64 + L)*8;
    const short8 qh = *(const short8*)(qkt_hi + qoff);
    const short8 ql = *(const short8*)(qkt_lo + qoff);

    float m_run = -INFINITY, l_run = 0.0f;
    f32x16 O0 = (f32x16)0.0f, O1 = (f32x16)0.0f;
    const int cg0 = chalf*4 + w*2;
    const unsigned short* vt0 = vbf + ((size_t)(b*8 + cg0)*49)*2048 + (size_t)L*8;
    const unsigned short* vt1 = vbf + ((size_t)(b*8 + cg0 + 1)*49)*2048 + (size_t)L*8;
    const unsigned short* kbh = Kf_hi + (size_t)b*49*2048 + (size_t)L*8;
    const unsigned short* kbl = Kf_lo + (size_t)b*49*2048 + (size_t)L*8;

    for (int jtl = 0; jtl < njt; jtl++) {
        const int jt = jt0 + jtl;
        const int buf = jtl & 1;

        short8 Va[4], Vb[4];
#pragma unroll
        for (int s = 0; s < 4; s++) {
            Va[s] = *(const short8*)(vt0 + jt*2048 + s*512);
            Vb[s] = *(const short8*)(vt1 + jt*2048 + s*512);
        }

        f32x4 sacc[4];
#pragma unroll
        for (int tj = 0; tj < 4; tj++) {
            const short8 kh = *(const short8*)(kbh + jt*2048 + tj*512);
            const short8 kl = *(const short8*)(kbl + jt*2048 + tj*512);
            f32x4 a = (f32x4)0.0f;
            a = MFMA16(kh, qh, a);
            a = MFMA16(kh, ql, a);
            a = MFMA16(kl, qh, a);
            sacc[tj] = a;
        }
        float mt0 = fmaxf(fmaxf(sacc[0][0], sacc[0][1]), fmaxf(sacc[0][2], sacc[0][3]));
        float mt1 = fmaxf(fmaxf(sacc[1][0], sacc[1][1]), fmaxf(sacc[1][2], sacc[1][3]));
        float mt2 = fmaxf(fmaxf(sacc[2][0], sacc[2][1]), fmaxf(sacc[2][2], sacc[2][3]));
        float mt3 = fmaxf(fmaxf(sacc[3][0], sacc[3][1]), fmaxf(sacc[3][2], sacc[3][3]));
        float mx = fmaxf(fmaxf(mt0, mt1), fmaxf(mt2, mt3));
        mx = fmaxf(mx, __shfl_xor(mx, 16));
        mx = fmaxf(mx, __shfl_xor(mx, 32));

        float alpha = 1.0f;
        if (__any(mx > m_run + 8.0f)) {
            const float m_new = fmaxf(m_run, mx);
            alpha = exp2_hw(m_run - m_new);
            m_run = m_new;
        }

#pragma unroll
        for (int tj = 0; tj < 4; tj++)
#pragma unroll
            for (int r = 0; r < 4; r++)
                sacc[tj][r] = exp2_hw(sacc[tj][r] - m_run);
        float s0 = (sacc[0][0] + sacc[0][1]) + (sacc[0][2] + sacc[0][3]);
        float s1 = (sacc[1][0] + sacc[1][1]) + (sacc[1][2] + sacc[1][3]);
        float s2 = (sacc[2][0] + sacc[2][1]) + (sacc[2][2] + sacc[2][3]);
        float s3 = (sacc[3][0] + sacc[3][1]) + (sacc[3][2] + sacc[3][3]);
        float ps = (s0 + s1) + (s2 + s3);
        ps += __shfl_xor(ps, 16);
        ps += __shfl_xor(ps, 32);
        l_run = l_run * alpha + ps;

        {
            unsigned short* prow = &P[buf][(w*16 + ln)*PSTR];
#pragma unroll
            for (int tj = 0; tj < 4; tj++) {
                uint2 pp;
                pp.x = cvt_pk_bf16(sacc[tj][0], sacc[tj][1]);
                pp.y = cvt_pk_bf16(sacc[tj][2], sacc[tj][3]);
                *(uint2*)(prow + tj*16 + quad*4) = pp;
            }
        }
        if (quad == 0) alphaL[buf][w*16 + ln] = alpha;

        __syncthreads();

        const float a = alphaL[buf][l32];
        if (__any(a != 1.0f)) {
#pragma unroll
            for (int rg = 0; rg < 16; rg++) { O0[rg] *= a; O1[rg] *= a; }
        }
        short8 Bp[4];
#pragma unroll
        for (int s = 0; s < 4; s++) {
            Bp[s] = *(const short8*)&P[buf][l32*PSTR + s*16 + h32*8];
            O0 = MFMA32(Va[s], Bp[s], O0);
        }
#pragma unroll
        for (int s = 0; s < 4; s++)
            O1 = MFMA32(Vb[s], Bp[s], O1);
    }

    if (chalf == 0 && quad == 0) {
        const int i = i_base + w*16 + ln;
        mlbase[jh*BN_ + b*N_ + i]       = m_run;
        mlbase[(2 + jh)*BN_ + b*N_ + i] = l_run;
    }
    unsigned short* OP = jh ? op1 : op0;
    const int pix = i_base + l32;
#pragma unroll
    for (int g = 0; g < 2; g++) {
        const f32x16 Ot = g ? O1 : O0;
        const int cg = chalf*128 + w*64 + g*32;
#pragma unroll
        for (int reg = 0; reg < 16; reg++) {
            const int c = cg + (reg & 3) + 8*(reg >> 2) + 4*h32;
            OP[(size_t)(b*C_ + c)*N_ + pix] = f2bf(Ot[reg]);
        }
    }
}

// ---------------------------------------------------------------------------
// Kernel 3b: per-pixel combine coefficients (exp2 domain, gamma folded).
// ---------------------------------------------------------------------------
__global__ __launch_bounds__(256) void coef_pre(
    const float* __restrict__ mlbase, const float* __restrict__ gptr,
    float* __restrict__ coef)
{
    const int i = blockIdx.x*256 + threadIdx.x;   // 0..BN-1
    const float m0 = mlbase[i],        m1 = mlbase[BN_ + i];
    const float l0 = mlbase[2*BN_ + i], l1 = mlbase[3*BN_ + i];
    const float mm = fmaxf(m0, m1);
    const float a0 = exp2_hw(m0 - mm), a1 = exp2_hw(m1 - mm);
    const float inv = gptr[0] / (a0*l0 + a1*l1);
    coef[2*i]   = a0 * inv;
    coef[2*i+1] = a1 * inv;
}

// ---------------------------------------------------------------------------
// Kernel 4: combine, vectorized: 4 px/thread, ushort4/float4.
// ---------------------------------------------------------------------------
__global__ __launch_bounds__(256) void combine(
    const unsigned short* __restrict__ op0, const unsigned short* __restrict__ op1,
    const float* __restrict__ coef,
    const float* __restrict__ x, float* __restrict__ out)
{
    const int bc = blockIdx.x;
    const int b = bc >> 8;
    const size_t base = (size_t)bc * N_;
    const float2* cf = (const float2*)coef + (size_t)b * N_;
    for (int pq = threadIdx.x; pq < 784; pq += 256) {
        const int p0 = pq * 4;
        const ushort4 o0 = *(const ushort4*)(op0 + base + p0);
        const ushort4 o1 = *(const ushort4*)(op1 + base + p0);
        const float4 xx = *(const float4*)(x + base + p0);
        float4 r;
        { const float2 c = cf[p0 + 0]; r.x = xx.x + c.x*bf2f(o0.x) + c.y*bf2f(o1.x); }
        { const float2 c = cf[p0 + 1]; r.y = xx.y + c.x*bf2f(o0.y) + c.y*bf2f(o1.y); }
        { const float2 c = cf[p0 + 2]; r.z = xx.z + c.x*bf2f(o0.z) + c.y*bf2f(o1.z); }
        { const float2 c = cf[p0 + 3]; r.w = xx.w + c.x*bf2f(o0.w) + c.y*bf2f(o1.w); }
        *(float4*)(out + base + p0) = r;
    }
}

// ---------------------------------------------------------------------------
extern "C" void kernel_launch(void* const* d_in, const int* in_sizes, int n_in,
                              void* d_out, int out_size, void* d_ws, size_t ws_size,
                              hipStream_t stream)
{
    (void)in_sizes; (void)n_in; (void)out_size; (void)ws_size;
    const float* x  = (const float*)d_in[0];
    const float* wq = (const float*)d_in[1];
    const float* bq = (const float*)d_in[2];
    const float* wk = (const float*)d_in[3];
    const float* bk = (const float*)d_in[4];
    const float* wv = (const float*)d_in[5];
    const float* bv = (const float*)d_in[6];
    const float* gm = (const float*)d_in[7];
    float* out = (float*)d_out;

    unsigned short* u = (unsigned short*)d_ws;
    unsigned short* xhi = u;                      // conv input; later O-partial jh=0
    unsigned short* xlo = u + XT_ELEMS;           // conv input; later O-partial jh=1
    unsigned short* Ahi = u + AHI_OFF;            // Af weights; later m/l
    unsigned short* Alo = u + ALO_OFF;            // Af lo; later coef table
    unsigned short* qkt_hi = u + QKT_HI_OFF;      // [Qf_hi | Kf_hi]
    unsigned short* qkt_lo = u + QKT_LO_OFF;      // [Qf_lo | Kf_lo]
    unsigned short* vbf = u + VBF_OFF;            // Vf fragment-order
    float* mlbase = (float*)Ahi;                  // 4 * B*N floats
    float* coef = (float*)Alo;                    // 2 * B*N floats

    hipLaunchKernelGGL(zero_pads, dim3(480), dim3(256), 0, stream, xhi, xlo);
    hipLaunchKernelGGL(prep_x, dim3(4, 56, 8), dim3(256), 0, stream, x, xhi, xlo);
    hipLaunchKernelGGL(prep_w, dim3(2880), dim3(256), 0, stream, wq, wk, wv, Ahi, Alo);
    hipLaunchKernelGGL(conv_fused, dim3(8, 56, 2), dim3(256), 0, stream,
                       xhi, xlo, Ahi, Alo, bq, bk, bv, qkt_hi, qkt_lo, vbf);
    hipLaunchKernelGGL(attn_flash2w, dim3(98*8, 2, 2), dim3(128), 0, stream,
                       qkt_hi, qkt_lo, vbf, xhi, xlo, mlbase);
    hipLaunchKernelGGL(coef_pre, dim3(98), dim3(256), 0, stream, mlbase, gm, coef);
    hipLaunchKernelGGL(combine, dim3(2048), dim3(256), 0, stream,
                       xhi, xlo, coef, x, out);
}